// Round 1
// baseline (2412.310 us; speedup 1.0000x reference)
//
#include <hip/hip_runtime.h>
#include <math.h>

#define NEG_SLOPE 0.2f

__device__ __forceinline__ unsigned flipf(float f) {
    unsigned b = __float_as_uint(f);
    return (b & 0x80000000u) ? ~b : (b | 0x80000000u);
}
__device__ __forceinline__ float unflipf(unsigned u) {
    return (u & 0x80000000u) ? __uint_as_float(u ^ 0x80000000u)
                             : __uint_as_float(~u);
}

// x[i] = concat(pos[i] (3), emb[z[i]] (125))  -> [N,128]
__global__ void build_x(const float* __restrict__ pos, const int* __restrict__ z,
                        const float* __restrict__ emb, float* __restrict__ x, int n) {
    int id = blockIdx.x * blockDim.x + threadIdx.x;
    if (id >= n * 128) return;
    int node = id >> 7, k = id & 127;
    float v;
    if (k < 3) v = pos[node * 3 + k];
    else       v = emb[z[node] * 125 + (k - 3)];
    x[id] = v;
}

// Y[N,HOUT] = X[N,128] @ W[128,HOUT] (+bias). W staged in LDS.
template <int HOUT, int ROWS>
__global__ void gemm_x128(const float* __restrict__ X, const float* __restrict__ W,
                          const float* __restrict__ bias, float* __restrict__ Y, int n) {
    __shared__ float Wl[128 * HOUT];
    __shared__ float Xl[ROWS][128];
    for (int i = threadIdx.x; i < 128 * HOUT; i += blockDim.x) Wl[i] = W[i];
    int row0 = blockIdx.x * ROWS;
    for (int i = threadIdx.x; i < ROWS * 128; i += blockDim.x) {
        int r = row0 + (i >> 7);
        Xl[i >> 7][i & 127] = (r < n) ? X[(size_t)r * 128 + (i & 127)] : 0.f;
    }
    __syncthreads();
    const int RPI = 256 / HOUT;          // rows in flight per iteration
    int lr = threadIdx.x / HOUT;
    int j  = threadIdx.x % HOUT;
    for (int rr = lr; rr < ROWS; rr += RPI) {
        int r = row0 + rr;
        if (r >= n) break;
        float acc = bias ? bias[j] : 0.f;
        #pragma unroll 8
        for (int k = 0; k < 128; ++k) acc += Xl[rr][k] * Wl[k * HOUT + j];
        Y[(size_t)r * HOUT + j] = acc;
    }
}

// ssrc[i] = h[i].a_s ; sdst[i] = h[i].a_d  (one wave per node)
__global__ void node_dots(const float* __restrict__ h, const float* __restrict__ a_s,
                          const float* __restrict__ a_d, float* __restrict__ ssrc,
                          float* __restrict__ sdst, int n) {
    int gid = blockIdx.x * blockDim.x + threadIdx.x;
    int wid = gid >> 6, lane = gid & 63;
    if (wid >= n) return;
    float h0 = h[(size_t)wid * 128 + lane];
    float h1 = h[(size_t)wid * 128 + 64 + lane];
    float vs = h0 * a_s[lane] + h1 * a_s[64 + lane];
    float vd = h0 * a_d[lane] + h1 * a_d[64 + lane];
    #pragma unroll
    for (int o = 32; o; o >>= 1) { vs += __shfl_down(vs, o); vd += __shfl_down(vd, o); }
    if (lane == 0) { ssrc[wid] = vs; sdst[wid] = vd; }
}

// per-edge score + segment max (flipped-uint atomicMax)
__global__ void edge_score(const int* __restrict__ ei, int E,
                           const float* __restrict__ ssrc, const float* __restrict__ sdst,
                           float* __restrict__ sc, unsigned* __restrict__ m_u, int n) {
    int e = blockIdx.x * blockDim.x + threadIdx.x;
    int Etot = E + n;
    if (e >= Etot) return;
    int s, d;
    if (e < E) { s = ei[e]; d = ei[E + e]; } else { s = d = e - E; }
    float v = ssrc[s] + sdst[d];
    v = v > 0.f ? v : NEG_SLOPE * v;
    sc[e] = v;
    atomicMax(&m_u[d], flipf(v));
}

// e = exp(s - m[dst]); denom[dst] += e
__global__ void edge_exp(const int* __restrict__ ei, int E, float* __restrict__ sc,
                         float* __restrict__ denom, const unsigned* __restrict__ m_u, int n) {
    int e = blockIdx.x * blockDim.x + threadIdx.x;
    int Etot = E + n;
    if (e >= Etot) return;
    int d = (e < E) ? ei[E + e] : (e - E);
    float ev = expf(sc[e] - unflipf(m_u[d]));
    sc[e] = ev;
    atomicAdd(&denom[d], ev);
}

// accum[dst] += e * h[src]  (one wave per edge, 2 feats/lane)
__global__ void edge_accum(const int* __restrict__ ei, int E, const float* __restrict__ sc,
                           const float* __restrict__ h, float* __restrict__ accum, int n) {
    int gid = blockIdx.x * blockDim.x + threadIdx.x;
    int wid = gid >> 6, lane = gid & 63;
    int Etot = E + n;
    if (wid >= Etot) return;
    int s, d;
    if (wid < E) { s = ei[wid]; d = ei[E + wid]; } else { s = d = wid - E; }
    float w = sc[wid];
    const float* hs = h + (size_t)s * 128;
    float* ad = accum + (size_t)d * 128;
    atomicAdd(&ad[lane],      w * hs[lane]);
    atomicAdd(&ad[lane + 64], w * hs[lane + 64]);
}

// out = elu(accum/denom + bias), in place
__global__ void node_finish(float* __restrict__ accum, const float* __restrict__ denom,
                            const float* __restrict__ bias, int n) {
    int id = blockIdx.x * blockDim.x + threadIdx.x;
    if (id >= n * 128) return;
    int node = id >> 7, k = id & 127;
    float v = accum[id] / denom[node] + bias[k];
    v = v > 0.f ? v : (expf(v) - 1.f);
    accum[id] = v;
}

// per-graph sum + count
__global__ void pool_accum(const float* __restrict__ y, const int* __restrict__ batch,
                           float* __restrict__ gsum, float* __restrict__ gcnt, int n) {
    int id = blockIdx.x * blockDim.x + threadIdx.x;
    if (id >= n * 32) return;
    int node = id >> 5, c = id & 31;
    int g = batch[node];
    atomicAdd(&gsum[g * 32 + c], y[id]);
    if (c == 0) atomicAdd(&gcnt[g], 1.f);
}

__global__ void pool_final(const float* __restrict__ gsum, const float* __restrict__ gcnt,
                           float* __restrict__ out, int total) {
    int id = blockIdx.x * blockDim.x + threadIdx.x;
    if (id >= total) return;
    int g = id >> 5;
    out[id] = gsum[id] / fmaxf(gcnt[g], 1.f);
}

extern "C" void kernel_launch(void* const* d_in, const int* in_sizes, int n_in,
                              void* d_out, int out_size, void* d_ws, size_t ws_size,
                              hipStream_t stream) {
    const float* pos  = (const float*)d_in[0];
    const int*   z    = (const int*)d_in[1];
    const int*   ei   = (const int*)d_in[2];
    const int*   batch= (const int*)d_in[3];
    const float* emb  = (const float*)d_in[4];
    const float* W1   = (const float*)d_in[5];
    const float* a1s  = (const float*)d_in[6];
    const float* a1d  = (const float*)d_in[7];
    const float* b1   = (const float*)d_in[8];
    const float* W2   = (const float*)d_in[9];
    const float* a2s  = (const float*)d_in[10];
    const float* a2d  = (const float*)d_in[11];
    const float* b2   = (const float*)d_in[12];
    const float* Wlin = (const float*)d_in[13];
    const float* blin = (const float*)d_in[14];

    const int N = in_sizes[0] / 3;        // 50000
    const int E = in_sizes[2] / 2;        // 1600000
    const int Etot = E + N;
    const int G = out_size / 32;          // 64

    char* ws = (char*)d_ws;
    size_t NB = (size_t)N * 128 * sizeof(float);
    float*    buf0  = (float*)ws;                 // x / h2 / y
    float*    buf1  = (float*)(ws + NB);          // h1 / accum2->x3
    float*    buf2  = (float*)(ws + 2 * NB);      // accum1->x2
    float*    ssrc  = (float*)(ws + 3 * NB);
    float*    sdst  = ssrc + N;
    unsigned* m_u   = (unsigned*)(sdst + N);
    float*    denom = (float*)(m_u + N);
    float*    esc   = denom + N;                  // E+N edge scratch
    float*    gsum  = esc + Etot;
    float*    gcnt  = gsum + (size_t)G * 32;

    const int TB = 256;
    dim3 blk(TB);
    int gElem   = (N * 128 + TB - 1) / TB;
    int gEdge   = (Etot + TB - 1) / TB;
    int gEdgeW  = ((size_t)Etot * 64 + TB - 1) / TB;
    int gNodeW  = ((size_t)N * 64 + TB - 1) / TB;
    int gGemm   = (N + 31) / 32;
    int gGemmO  = (N + 63) / 64;
    int gPool   = (N * 32 + TB - 1) / TB;

    // ---------- layer 1 ----------
    hipMemsetAsync(buf2, 0, NB, stream);                       // accum1
    hipMemsetAsync(m_u, 0, (size_t)N * 8, stream);             // m_u + denom (adjacent)
    build_x<<<gElem, blk, 0, stream>>>(pos, z, emb, buf0, N);
    gemm_x128<128, 32><<<gGemm, blk, 0, stream>>>(buf0, W1, nullptr, buf1, N);
    node_dots<<<gNodeW, blk, 0, stream>>>(buf1, a1s, a1d, ssrc, sdst, N);
    edge_score<<<gEdge, blk, 0, stream>>>(ei, E, ssrc, sdst, esc, m_u, N);
    edge_exp<<<gEdge, blk, 0, stream>>>(ei, E, esc, denom, m_u, N);
    edge_accum<<<gEdgeW, blk, 0, stream>>>(ei, E, esc, buf1, buf2, N);
    node_finish<<<gElem, blk, 0, stream>>>(buf2, denom, b1, N);

    // ---------- layer 2 ----------
    hipMemsetAsync(buf1, 0, NB, stream);                       // accum2
    hipMemsetAsync(m_u, 0, (size_t)N * 8, stream);             // m_u + denom
    gemm_x128<128, 32><<<gGemm, blk, 0, stream>>>(buf2, W2, nullptr, buf0, N);
    node_dots<<<gNodeW, blk, 0, stream>>>(buf0, a2s, a2d, ssrc, sdst, N);
    edge_score<<<gEdge, blk, 0, stream>>>(ei, E, ssrc, sdst, esc, m_u, N);
    edge_exp<<<gEdge, blk, 0, stream>>>(ei, E, esc, denom, m_u, N);
    edge_accum<<<gEdgeW, blk, 0, stream>>>(ei, E, esc, buf0, buf1, N);
    node_finish<<<gElem, blk, 0, stream>>>(buf1, denom, b2, N);

    // ---------- linear + pool ----------
    hipMemsetAsync(gsum, 0, ((size_t)G * 32 + G) * sizeof(float), stream);
    gemm_x128<32, 64><<<gGemmO, blk, 0, stream>>>(buf1, Wlin, blin, buf0, N);
    pool_accum<<<gPool, blk, 0, stream>>>(buf0, batch, gsum, gcnt, N);
    pool_final<<<(G * 32 + TB - 1) / TB, blk, 0, stream>>>(gsum, gcnt, (float*)d_out, G * 32);
}

// Round 2
// 1136.643 us; speedup vs baseline: 2.1223x; 2.1223x over previous
//
#include <hip/hip_runtime.h>
#include <math.h>

#define NEG_SLOPE 0.2f

// x[i] = concat(pos[i] (3), emb[z[i]] (125))  -> [N,128]
__global__ void build_x(const float* __restrict__ pos, const int* __restrict__ z,
                        const float* __restrict__ emb, float* __restrict__ x, int n) {
    int id = blockIdx.x * blockDim.x + threadIdx.x;
    if (id >= n * 128) return;
    int node = id >> 7, k = id & 127;
    float v;
    if (k < 3) v = pos[node * 3 + k];
    else       v = emb[z[node] * 125 + (k - 3)];
    x[id] = v;
}

// Y[N,HOUT] = X[N,128] @ W[128,HOUT] (+bias). W staged in LDS.
template <int HOUT, int ROWS>
__global__ void gemm_x128(const float* __restrict__ X, const float* __restrict__ W,
                          const float* __restrict__ bias, float* __restrict__ Y, int n) {
    __shared__ float Wl[128 * HOUT];
    __shared__ float Xl[ROWS][128];
    for (int i = threadIdx.x; i < 128 * HOUT; i += blockDim.x) Wl[i] = W[i];
    int row0 = blockIdx.x * ROWS;
    for (int i = threadIdx.x; i < ROWS * 128; i += blockDim.x) {
        int r = row0 + (i >> 7);
        Xl[i >> 7][i & 127] = (r < n) ? X[(size_t)r * 128 + (i & 127)] : 0.f;
    }
    __syncthreads();
    const int RPI = 256 / HOUT;          // rows in flight per iteration
    int lr = threadIdx.x / HOUT;
    int j  = threadIdx.x % HOUT;
    for (int rr = lr; rr < ROWS; rr += RPI) {
        int r = row0 + rr;
        if (r >= n) break;
        float acc = bias ? bias[j] : 0.f;
        #pragma unroll 8
        for (int k = 0; k < 128; ++k) acc += Xl[rr][k] * Wl[k * HOUT + j];
        Y[(size_t)r * HOUT + j] = acc;
    }
}

// ssrc[i] = h[i].a_s ; sdst[i] = h[i].a_d  (one wave per node)
__global__ void node_dots(const float* __restrict__ h, const float* __restrict__ a_s,
                          const float* __restrict__ a_d, float* __restrict__ ssrc,
                          float* __restrict__ sdst, int n) {
    int gid = blockIdx.x * blockDim.x + threadIdx.x;
    int wid = gid >> 6, lane = gid & 63;
    if (wid >= n) return;
    float h0 = h[(size_t)wid * 128 + lane];
    float h1 = h[(size_t)wid * 128 + 64 + lane];
    float vs = h0 * a_s[lane] + h1 * a_s[64 + lane];
    float vd = h0 * a_d[lane] + h1 * a_d[64 + lane];
    #pragma unroll
    for (int o = 32; o; o >>= 1) { vs += __shfl_down(vs, o); vd += __shfl_down(vd, o); }
    if (lane == 0) { ssrc[wid] = vs; sdst[wid] = vd; }
}

// ---------------- CSR build (once per call; graph shared by both layers) ----

__global__ void deg_hist(const int* __restrict__ ei, int E, int n, int* __restrict__ deg) {
    int e = blockIdx.x * blockDim.x + threadIdx.x;
    if (e >= E + n) return;
    int d = (e < E) ? ei[E + e] : (e - E);
    atomicAdd(&deg[d], 1);
}

// in-place per-block exclusive scan; part[b] = block total
__global__ void scan1(int* __restrict__ deg, int* __restrict__ part, int n) {
    __shared__ int s[256];
    int t = threadIdx.x;
    int i = blockIdx.x * 256 + t;
    int v = (i < n) ? deg[i] : 0;
    s[t] = v; __syncthreads();
    for (int o = 1; o < 256; o <<= 1) {
        int tv = (t >= o) ? s[t - o] : 0;
        __syncthreads();
        s[t] += tv;
        __syncthreads();
    }
    if (i < n) deg[i] = s[t] - v;            // exclusive
    if (t == 255) part[blockIdx.x] = s[255]; // inclusive total
}

__global__ void scan2(int* __restrict__ part, int nparts) {
    __shared__ int s[256];
    int t = threadIdx.x;
    int v = (t < nparts) ? part[t] : 0;
    s[t] = v; __syncthreads();
    for (int o = 1; o < 256; o <<= 1) {
        int tv = (t >= o) ? s[t - o] : 0;
        __syncthreads();
        s[t] += tv;
        __syncthreads();
    }
    if (t < nparts) part[t] = s[t] - v;      // exclusive
}

__global__ void scan3(const int* __restrict__ deg, const int* __restrict__ part,
                      int* __restrict__ rowptr, int* __restrict__ cursor, int n, int Etot) {
    int i = blockIdx.x * blockDim.x + threadIdx.x;
    if (i == 0) rowptr[n] = Etot;
    if (i >= n) return;
    int v = deg[i] + part[blockIdx.x * 256 / 256 == 0 ? blockIdx.x : blockIdx.x]; // placeholder
    v = deg[i] + part[i >> 8];
    rowptr[i] = v;
    cursor[i] = v;
}

__global__ void edge_scatter(const int* __restrict__ ei, int E, int n,
                             int* __restrict__ cursor, int* __restrict__ csr_src) {
    int e = blockIdx.x * blockDim.x + threadIdx.x;
    if (e >= E + n) return;
    int s, d;
    if (e < E) { s = ei[e]; d = ei[E + e]; } else { s = d = e - E; }
    int p = atomicAdd(&cursor[d], 1);
    csr_src[p] = s;
}

// ------------- fused GAT aggregation: one wave per dst node -----------------
// softmax over incoming edges (exact 2-pass), weighted sum of h[src], +bias, ELU
__global__ void gat_gather(const int* __restrict__ rowptr, const int* __restrict__ csr_src,
                           const float* __restrict__ ssrc, const float* __restrict__ sdst,
                           const float* __restrict__ h, const float* __restrict__ bias,
                           float* __restrict__ out, int n) {
    int wid = (blockIdx.x * blockDim.x + threadIdx.x) >> 6;
    int lane = threadIdx.x & 63;
    if (wid >= n) return;
    int beg = rowptr[wid], end = rowptr[wid + 1];
    float sd = sdst[wid];

    // pass 1: exact segment max
    float m = -INFINITY;
    for (int base = beg; base < end; base += 64) {
        int i = base + lane;
        float s = -INFINITY;
        if (i < end) {
            float v = ssrc[csr_src[i]] + sd;
            s = v > 0.f ? v : NEG_SLOPE * v;
        }
        m = fmaxf(m, s);
    }
    #pragma unroll
    for (int o = 32; o; o >>= 1) m = fmaxf(m, __shfl_xor(m, o));

    // pass 2: exp, denom, weighted feature gather (float2: feats 2*lane, 2*lane+1)
    float2 acc = make_float2(0.f, 0.f);
    float den = 0.f;
    for (int base = beg; base < end; base += 64) {
        int i = base + lane;
        int cnt = min(64, end - base);
        int src = 0;
        float w = 0.f;
        if (i < end) {
            src = csr_src[i];
            float v = ssrc[src] + sd;
            v = v > 0.f ? v : NEG_SLOPE * v;
            w = expf(v - m);
        }
        den += w;
        for (int j = 0; j < cnt; ++j) {
            float wj = __shfl(w, j);
            int  sj  = __shfl(src, j);
            float2 hv = ((const float2*)(h + (size_t)sj * 128))[lane];
            acc.x += wj * hv.x;
            acc.y += wj * hv.y;
        }
    }
    #pragma unroll
    for (int o = 32; o; o >>= 1) den += __shfl_xor(den, o);

    float o0 = acc.x / den + bias[2 * lane];
    float o1 = acc.y / den + bias[2 * lane + 1];
    o0 = o0 > 0.f ? o0 : (expf(o0) - 1.f);
    o1 = o1 > 0.f ? o1 : (expf(o1) - 1.f);
    ((float2*)(out + (size_t)wid * 128))[lane] = make_float2(o0, o1);
}

// ---------------- pooling ---------------------------------------------------
__global__ void pool_accum(const float* __restrict__ y, const int* __restrict__ batch,
                           float* __restrict__ gsum, float* __restrict__ gcnt, int n) {
    int id = blockIdx.x * blockDim.x + threadIdx.x;
    if (id >= n * 32) return;
    int node = id >> 5, c = id & 31;
    int g = batch[node];
    atomicAdd(&gsum[g * 32 + c], y[id]);
    if (c == 0) atomicAdd(&gcnt[g], 1.f);
}

__global__ void pool_final(const float* __restrict__ gsum, const float* __restrict__ gcnt,
                           float* __restrict__ out, int total) {
    int id = blockIdx.x * blockDim.x + threadIdx.x;
    if (id >= total) return;
    int g = id >> 5;
    out[id] = gsum[id] / fmaxf(gcnt[g], 1.f);
}

extern "C" void kernel_launch(void* const* d_in, const int* in_sizes, int n_in,
                              void* d_out, int out_size, void* d_ws, size_t ws_size,
                              hipStream_t stream) {
    const float* pos  = (const float*)d_in[0];
    const int*   z    = (const int*)d_in[1];
    const int*   ei   = (const int*)d_in[2];
    const int*   batch= (const int*)d_in[3];
    const float* emb  = (const float*)d_in[4];
    const float* W1   = (const float*)d_in[5];
    const float* a1s  = (const float*)d_in[6];
    const float* a1d  = (const float*)d_in[7];
    const float* b1   = (const float*)d_in[8];
    const float* W2   = (const float*)d_in[9];
    const float* a2s  = (const float*)d_in[10];
    const float* a2d  = (const float*)d_in[11];
    const float* b2   = (const float*)d_in[12];
    const float* Wlin = (const float*)d_in[13];
    const float* blin = (const float*)d_in[14];

    const int N = in_sizes[0] / 3;        // 50000
    const int E = in_sizes[2] / 2;        // 1600000
    const int Etot = E + N;
    const int G = out_size / 32;          // 64

    char* ws = (char*)d_ws;
    size_t NB = (size_t)N * 128 * sizeof(float);
    float* buf0   = (float*)ws;                    // x / h2 / y
    float* buf1   = (float*)(ws + NB);             // h1 / out2
    float* buf2   = (float*)(ws + 2 * NB);         // out1 (=x for layer2)
    float* ssrc   = (float*)(ws + 3 * NB);
    float* sdst   = ssrc + N;
    int*   rowptr = (int*)(sdst + N);              // N+1
    int*   cursor = rowptr + N + 1;                // N
    int*   deg    = cursor + N;                    // N (also scan tmp, in place)
    int*   part   = deg + N;                       // 256
    int*   csrs   = part + 256;                    // Etot
    float* gsum   = (float*)(csrs + Etot);         // G*32
    float* gcnt   = gsum + (size_t)G * 32;         // G

    const int TB = 256;
    dim3 blk(TB);
    int gElem  = (N * 128 + TB - 1) / TB;
    int gEdge  = (Etot + TB - 1) / TB;
    int gNodeW = ((size_t)N * 64 + TB - 1) / TB;
    int gGemm  = (N + 31) / 32;
    int gGemmO = (N + 63) / 64;
    int gPool  = (N * 32 + TB - 1) / TB;
    int nparts = (N + 255) / 256;
    int gGat   = (N + 3) / 4;                      // 4 waves (4 dsts) per block

    // ---------- CSR build (graph shared by both layers) ----------
    hipMemsetAsync(deg, 0, (size_t)N * sizeof(int), stream);
    deg_hist<<<gEdge, blk, 0, stream>>>(ei, E, N, deg);
    scan1<<<nparts, blk, 0, stream>>>(deg, part, N);
    scan2<<<1, blk, 0, stream>>>(part, nparts);
    scan3<<<nparts, blk, 0, stream>>>(deg, part, rowptr, cursor, N, Etot);
    edge_scatter<<<gEdge, blk, 0, stream>>>(ei, E, N, cursor, csrs);

    // ---------- layer 1 ----------
    build_x<<<gElem, blk, 0, stream>>>(pos, z, emb, buf0, N);
    gemm_x128<128, 32><<<gGemm, blk, 0, stream>>>(buf0, W1, nullptr, buf1, N);
    node_dots<<<gNodeW, blk, 0, stream>>>(buf1, a1s, a1d, ssrc, sdst, N);
    gat_gather<<<gGat, blk, 0, stream>>>(rowptr, csrs, ssrc, sdst, buf1, b1, buf2, N);

    // ---------- layer 2 ----------
    gemm_x128<128, 32><<<gGemm, blk, 0, stream>>>(buf2, W2, nullptr, buf0, N);
    node_dots<<<gNodeW, blk, 0, stream>>>(buf0, a2s, a2d, ssrc, sdst, N);
    gat_gather<<<gGat, blk, 0, stream>>>(rowptr, csrs, ssrc, sdst, buf0, b2, buf1, N);

    // ---------- linear + pool ----------
    hipMemsetAsync(gsum, 0, ((size_t)G * 32 + G) * sizeof(float), stream);
    gemm_x128<32, 64><<<gGemmO, blk, 0, stream>>>(buf1, Wlin, blin, buf0, N);
    pool_accum<<<gPool, blk, 0, stream>>>(buf0, batch, gsum, gcnt, N);
    pool_final<<<(G * 32 + TB - 1) / TB, blk, 0, stream>>>(gsum, gcnt, (float*)d_out, G * 32);
}

// Round 3
// 854.040 us; speedup vs baseline: 2.8246x; 1.3309x over previous
//
#include <hip/hip_runtime.h>
#include <math.h>

#define NEG_SLOPE 0.2f

// x[i] = concat(pos[i] (3), emb[z[i]] (125))  -> [N,128]
__global__ void build_x(const float* __restrict__ pos, const int* __restrict__ z,
                        const float* __restrict__ emb, float* __restrict__ x, int n) {
    int id = blockIdx.x * blockDim.x + threadIdx.x;
    if (id >= n * 128) return;
    int node = id >> 7, k = id & 127;
    float v;
    if (k < 3) v = pos[node * 3 + k];
    else       v = emb[z[node] * 125 + (k - 3)];
    x[id] = v;
}

// Y[N,HOUT] = X[N,128] @ W[128,HOUT] (+bias). W staged in LDS.
template <int HOUT, int ROWS>
__global__ void gemm_x128(const float* __restrict__ X, const float* __restrict__ W,
                          const float* __restrict__ bias, float* __restrict__ Y, int n) {
    __shared__ float Wl[128 * HOUT];
    __shared__ float Xl[ROWS][128];
    for (int i = threadIdx.x; i < 128 * HOUT; i += blockDim.x) Wl[i] = W[i];
    int row0 = blockIdx.x * ROWS;
    for (int i = threadIdx.x; i < ROWS * 128; i += blockDim.x) {
        int r = row0 + (i >> 7);
        Xl[i >> 7][i & 127] = (r < n) ? X[(size_t)r * 128 + (i & 127)] : 0.f;
    }
    __syncthreads();
    const int RPI = 256 / HOUT;          // rows in flight per iteration
    int lr = threadIdx.x / HOUT;
    int j  = threadIdx.x % HOUT;
    for (int rr = lr; rr < ROWS; rr += RPI) {
        int r = row0 + rr;
        if (r >= n) break;
        float acc = bias ? bias[j] : 0.f;
        #pragma unroll 8
        for (int k = 0; k < 128; ++k) acc += Xl[rr][k] * Wl[k * HOUT + j];
        Y[(size_t)r * HOUT + j] = acc;
    }
}

// ssrc[i] = h[i].a_s ; sdst[i] = h[i].a_d  (one wave per node)
__global__ void node_dots(const float* __restrict__ h, const float* __restrict__ a_s,
                          const float* __restrict__ a_d, float* __restrict__ ssrc,
                          float* __restrict__ sdst, int n) {
    int gid = blockIdx.x * blockDim.x + threadIdx.x;
    int wid = gid >> 6, lane = gid & 63;
    if (wid >= n) return;
    float h0 = h[(size_t)wid * 128 + lane];
    float h1 = h[(size_t)wid * 128 + 64 + lane];
    float vs = h0 * a_s[lane] + h1 * a_s[64 + lane];
    float vd = h0 * a_d[lane] + h1 * a_d[64 + lane];
    #pragma unroll
    for (int o = 32; o; o >>= 1) { vs += __shfl_down(vs, o); vd += __shfl_down(vd, o); }
    if (lane == 0) { ssrc[wid] = vs; sdst[wid] = vd; }
}

// ---------------- CSR build (once per call; graph shared by both layers) ----

__global__ void deg_hist(const int* __restrict__ ei, int E, int n, int* __restrict__ deg) {
    int e = blockIdx.x * blockDim.x + threadIdx.x;
    if (e >= E + n) return;
    int d = (e < E) ? ei[E + e] : (e - E);
    atomicAdd(&deg[d], 1);
}

// in-place per-block exclusive scan; part[b] = block total
__global__ void scan1(int* __restrict__ deg, int* __restrict__ part, int n) {
    __shared__ int s[256];
    int t = threadIdx.x;
    int i = blockIdx.x * 256 + t;
    int v = (i < n) ? deg[i] : 0;
    s[t] = v; __syncthreads();
    for (int o = 1; o < 256; o <<= 1) {
        int tv = (t >= o) ? s[t - o] : 0;
        __syncthreads();
        s[t] += tv;
        __syncthreads();
    }
    if (i < n) deg[i] = s[t] - v;            // exclusive
    if (t == 255) part[blockIdx.x] = s[255]; // inclusive total
}

__global__ void scan2(int* __restrict__ part, int nparts) {
    __shared__ int s[256];
    int t = threadIdx.x;
    int v = (t < nparts) ? part[t] : 0;
    s[t] = v; __syncthreads();
    for (int o = 1; o < 256; o <<= 1) {
        int tv = (t >= o) ? s[t - o] : 0;
        __syncthreads();
        s[t] += tv;
        __syncthreads();
    }
    if (t < nparts) part[t] = s[t] - v;      // exclusive
}

__global__ void scan3(const int* __restrict__ deg, const int* __restrict__ part,
                      int* __restrict__ rowptr, int* __restrict__ cursor, int n, int Etot) {
    int i = blockIdx.x * blockDim.x + threadIdx.x;
    if (i == 0) rowptr[n] = Etot;
    if (i >= n) return;
    int v = deg[i] + part[i >> 8];
    rowptr[i] = v;
    cursor[i] = v;
}

__global__ void edge_scatter(const int* __restrict__ ei, int E, int n,
                             int* __restrict__ cursor, int* __restrict__ csr_src) {
    int e = blockIdx.x * blockDim.x + threadIdx.x;
    if (e >= E + n) return;
    int s, d;
    if (e < E) { s = ei[e]; d = ei[E + e]; } else { s = d = e - E; }
    int p = atomicAdd(&cursor[d], 1);
    csr_src[p] = s;
}

// ------------- fused GAT aggregation: one wave per dst node -----------------
// softmax over incoming edges (exact 2-pass), weighted sum of h[src], +bias, ELU
__global__ void gat_gather(const int* __restrict__ rowptr, const int* __restrict__ csr_src,
                           const float* __restrict__ ssrc, const float* __restrict__ sdst,
                           const float* __restrict__ h, const float* __restrict__ bias,
                           float* __restrict__ out, int n) {
    int wid = (blockIdx.x * blockDim.x + threadIdx.x) >> 6;
    int lane = threadIdx.x & 63;
    if (wid >= n) return;
    int beg = rowptr[wid], end = rowptr[wid + 1];
    float sd = sdst[wid];

    // pass 1: exact segment max
    float m = -INFINITY;
    for (int base = beg; base < end; base += 64) {
        int i = base + lane;
        float s = -INFINITY;
        if (i < end) {
            float v = ssrc[csr_src[i]] + sd;
            s = v > 0.f ? v : NEG_SLOPE * v;
        }
        m = fmaxf(m, s);
    }
    #pragma unroll
    for (int o = 32; o; o >>= 1) m = fmaxf(m, __shfl_xor(m, o));

    // pass 2: exp, denom, weighted feature gather (float2: feats 2*lane, 2*lane+1)
    float2 acc = make_float2(0.f, 0.f);
    float den = 0.f;
    for (int base = beg; base < end; base += 64) {
        int i = base + lane;
        int cnt = min(64, end - base);
        int src = 0;
        float w = 0.f;
        if (i < end) {
            src = csr_src[i];
            float v = ssrc[src] + sd;
            v = v > 0.f ? v : NEG_SLOPE * v;
            w = expf(v - m);
        }
        den += w;
        for (int j = 0; j < cnt; ++j) {
            float wj = __shfl(w, j);
            int  sj  = __shfl(src, j);
            float2 hv = ((const float2*)(h + (size_t)sj * 128))[lane];
            acc.x += wj * hv.x;
            acc.y += wj * hv.y;
        }
    }
    #pragma unroll
    for (int o = 32; o; o >>= 1) den += __shfl_xor(den, o);

    float o0 = acc.x / den + bias[2 * lane];
    float o1 = acc.y / den + bias[2 * lane + 1];
    o0 = o0 > 0.f ? o0 : (expf(o0) - 1.f);
    o1 = o1 > 0.f ? o1 : (expf(o1) - 1.f);
    ((float2*)(out + (size_t)wid * 128))[lane] = make_float2(o0, o1);
}

// ---------------- pooling: one block per graph (batch is sorted) ------------
__global__ void pool_graph(const float* __restrict__ y, const int* __restrict__ batch,
                           float* __restrict__ out, int n, int G) {
    int g = blockIdx.x;
    // lower_bound(g) and lower_bound(g+1) over sorted batch
    int lo = 0, hi = n;
    while (lo < hi) { int mid = (lo + hi) >> 1; if (batch[mid] < g) lo = mid + 1; else hi = mid; }
    int beg = lo;
    hi = n;
    while (lo < hi) { int mid = (lo + hi) >> 1; if (batch[mid] < g + 1) lo = mid + 1; else hi = mid; }
    int end = lo;

    int c = threadIdx.x & 31;       // channel
    int sub = threadIdx.x >> 5;     // 8 row-lanes
    float acc = 0.f;
    for (int node = beg + sub; node < end; node += 8)
        acc += y[(size_t)node * 32 + c];

    __shared__ float ls[8][32];
    ls[sub][c] = acc;
    __syncthreads();
    if (sub == 0) {
        float s = 0.f;
        #pragma unroll
        for (int k = 0; k < 8; ++k) s += ls[k][c];
        out[g * 32 + c] = s / fmaxf((float)(end - beg), 1.f);
    }
}

extern "C" void kernel_launch(void* const* d_in, const int* in_sizes, int n_in,
                              void* d_out, int out_size, void* d_ws, size_t ws_size,
                              hipStream_t stream) {
    const float* pos  = (const float*)d_in[0];
    const int*   z    = (const int*)d_in[1];
    const int*   ei   = (const int*)d_in[2];
    const int*   batch= (const int*)d_in[3];
    const float* emb  = (const float*)d_in[4];
    const float* W1   = (const float*)d_in[5];
    const float* a1s  = (const float*)d_in[6];
    const float* a1d  = (const float*)d_in[7];
    const float* b1   = (const float*)d_in[8];
    const float* W2   = (const float*)d_in[9];
    const float* a2s  = (const float*)d_in[10];
    const float* a2d  = (const float*)d_in[11];
    const float* b2   = (const float*)d_in[12];
    const float* Wlin = (const float*)d_in[13];
    const float* blin = (const float*)d_in[14];

    const int N = in_sizes[0] / 3;        // 50000
    const int E = in_sizes[2] / 2;        // 1600000
    const int Etot = E + N;
    const int G = out_size / 32;          // 64

    char* ws = (char*)d_ws;
    size_t NB = (size_t)N * 128 * sizeof(float);
    float* buf0   = (float*)ws;                    // x / h2 / y
    float* buf1   = (float*)(ws + NB);             // h1 / out2
    float* buf2   = (float*)(ws + 2 * NB);         // out1 (=x for layer2)
    float* ssrc   = (float*)(ws + 3 * NB);
    float* sdst   = ssrc + N;
    int*   rowptr = (int*)(sdst + N);              // N+1
    int*   cursor = rowptr + N + 1;                // N
    int*   deg    = cursor + N;                    // N (scan in place)
    int*   part   = deg + N;                       // 256
    int*   csrs   = part + 256;                    // Etot

    const int TB = 256;
    dim3 blk(TB);
    int gElem  = (N * 128 + TB - 1) / TB;
    int gEdge  = (Etot + TB - 1) / TB;
    int gNodeW = ((size_t)N * 64 + TB - 1) / TB;
    int gGemm  = (N + 31) / 32;
    int gGemmO = (N + 63) / 64;
    int nparts = (N + 255) / 256;
    int gGat   = (N + 3) / 4;                      // 4 waves (4 dsts) per block

    // ---------- CSR build (graph shared by both layers) ----------
    hipMemsetAsync(deg, 0, (size_t)N * sizeof(int), stream);
    deg_hist<<<gEdge, blk, 0, stream>>>(ei, E, N, deg);
    scan1<<<nparts, blk, 0, stream>>>(deg, part, N);
    scan2<<<1, blk, 0, stream>>>(part, nparts);
    scan3<<<nparts, blk, 0, stream>>>(deg, part, rowptr, cursor, N, Etot);
    edge_scatter<<<gEdge, blk, 0, stream>>>(ei, E, N, cursor, csrs);

    // ---------- layer 1 ----------
    build_x<<<gElem, blk, 0, stream>>>(pos, z, emb, buf0, N);
    gemm_x128<128, 32><<<gGemm, blk, 0, stream>>>(buf0, W1, nullptr, buf1, N);
    node_dots<<<gNodeW, blk, 0, stream>>>(buf1, a1s, a1d, ssrc, sdst, N);
    gat_gather<<<gGat, blk, 0, stream>>>(rowptr, csrs, ssrc, sdst, buf1, b1, buf2, N);

    // ---------- layer 2 ----------
    gemm_x128<128, 32><<<gGemm, blk, 0, stream>>>(buf2, W2, nullptr, buf0, N);
    node_dots<<<gNodeW, blk, 0, stream>>>(buf0, a2s, a2d, ssrc, sdst, N);
    gat_gather<<<gGat, blk, 0, stream>>>(rowptr, csrs, ssrc, sdst, buf0, b2, buf1, N);

    // ---------- linear + pool ----------
    gemm_x128<32, 64><<<gGemmO, blk, 0, stream>>>(buf1, Wlin, blin, buf0, N);
    pool_graph<<<G, blk, 0, stream>>>(buf0, batch, (float*)d_out, N, G);
}

// Round 4
// 638.071 us; speedup vs baseline: 3.7806x; 1.3385x over previous
//
#include <hip/hip_runtime.h>
#include <math.h>

#define NEG_SLOPE 0.2f

// x[i] = concat(pos[i] (3), emb[z[i]] (125))  -> [N,128]
__global__ void build_x(const float* __restrict__ pos, const int* __restrict__ z,
                        const float* __restrict__ emb, float* __restrict__ x, int n) {
    int id = blockIdx.x * blockDim.x + threadIdx.x;
    if (id >= n * 128) return;
    int node = id >> 7, k = id & 127;
    float v;
    if (k < 3) v = pos[node * 3 + k];
    else       v = emb[z[node] * 125 + (k - 3)];
    x[id] = v;
}

// ---- register-tiled f32 GEMM: Y[N,128] = X[N,128] @ W[128,128] -------------
// 128 rows/block, 256 threads, 8x8 acc/thread, K chunks of 32 (32KB LDS).
__global__ __launch_bounds__(256)
void gemm128_tiled(const float* __restrict__ X, const float* __restrict__ W,
                   float* __restrict__ Y, int n) {
    __shared__ float Xt[32][128];   // [k][row]
    __shared__ float Wl[32][128];   // [k][col]
    int tid = threadIdx.x;
    int tx = tid & 15, ty = tid >> 4;
    int row0 = blockIdx.x * 128;
    float acc[8][8];
    #pragma unroll
    for (int i = 0; i < 8; ++i)
        #pragma unroll
        for (int j = 0; j < 8; ++j) acc[i][j] = 0.f;

    for (int k0 = 0; k0 < 128; k0 += 32) {
        __syncthreads();
        // stage X chunk transposed: 128 rows x 32 k
        #pragma unroll
        for (int i = 0; i < 4; ++i) {
            int f4 = tid + i * 256;                 // 0..1023
            int r = f4 >> 3, kp = (f4 & 7) << 2;    // 8 float4 per row
            int row = row0 + r;
            float4 v = (row < n) ? *(const float4*)(X + (size_t)row * 128 + k0 + kp)
                                 : make_float4(0.f, 0.f, 0.f, 0.f);
            Xt[kp + 0][r] = v.x; Xt[kp + 1][r] = v.y;
            Xt[kp + 2][r] = v.z; Xt[kp + 3][r] = v.w;
        }
        // stage W chunk: k0..k0+31, all 128 cols
        #pragma unroll
        for (int i = 0; i < 4; ++i) {
            int f4 = tid + i * 256;
            int kr = f4 >> 5, cp = (f4 & 31) << 2;
            *(float4*)(&Wl[kr][cp]) = *(const float4*)(W + (size_t)(k0 + kr) * 128 + cp);
        }
        __syncthreads();
        #pragma unroll 4
        for (int k = 0; k < 32; ++k) {
            float4 xa = *(float4*)(&Xt[k][ty * 8]);
            float4 xb = *(float4*)(&Xt[k][ty * 8 + 4]);
            float4 wa = *(float4*)(&Wl[k][tx * 4]);
            float4 wb = *(float4*)(&Wl[k][64 + tx * 4]);
            float xr[8] = {xa.x, xa.y, xa.z, xa.w, xb.x, xb.y, xb.z, xb.w};
            float wc[8] = {wa.x, wa.y, wa.z, wa.w, wb.x, wb.y, wb.z, wb.w};
            #pragma unroll
            for (int i = 0; i < 8; ++i)
                #pragma unroll
                for (int j = 0; j < 8; ++j) acc[i][j] += xr[i] * wc[j];
        }
    }
    #pragma unroll
    for (int i = 0; i < 8; ++i) {
        int row = row0 + ty * 8 + i;
        if (row >= n) break;
        *(float4*)(Y + (size_t)row * 128 + tx * 4) =
            make_float4(acc[i][0], acc[i][1], acc[i][2], acc[i][3]);
        *(float4*)(Y + (size_t)row * 128 + 64 + tx * 4) =
            make_float4(acc[i][4], acc[i][5], acc[i][6], acc[i][7]);
    }
}

// Y[N,HOUT] = X[N,128] @ W[128,HOUT] (+bias). W staged in LDS. (final 32-col layer)
template <int HOUT, int ROWS>
__global__ void gemm_x128(const float* __restrict__ X, const float* __restrict__ W,
                          const float* __restrict__ bias, float* __restrict__ Y, int n) {
    __shared__ float Wl[128 * HOUT];
    __shared__ float Xl[ROWS][128];
    for (int i = threadIdx.x; i < 128 * HOUT; i += blockDim.x) Wl[i] = W[i];
    int row0 = blockIdx.x * ROWS;
    for (int i = threadIdx.x; i < ROWS * 128; i += blockDim.x) {
        int r = row0 + (i >> 7);
        Xl[i >> 7][i & 127] = (r < n) ? X[(size_t)r * 128 + (i & 127)] : 0.f;
    }
    __syncthreads();
    const int RPI = 256 / HOUT;
    int lr = threadIdx.x / HOUT;
    int j  = threadIdx.x % HOUT;
    for (int rr = lr; rr < ROWS; rr += RPI) {
        int r = row0 + rr;
        if (r >= n) break;
        float acc = bias ? bias[j] : 0.f;
        #pragma unroll 8
        for (int k = 0; k < 128; ++k) acc += Xl[rr][k] * Wl[k * HOUT + j];
        Y[(size_t)r * HOUT + j] = acc;
    }
}

// ssrc[i] = h[i].a_s ; sdst[i] = h[i].a_d  (one wave per node)
__global__ void node_dots(const float* __restrict__ h, const float* __restrict__ a_s,
                          const float* __restrict__ a_d, float* __restrict__ ssrc,
                          float* __restrict__ sdst, int n) {
    int gid = blockIdx.x * blockDim.x + threadIdx.x;
    int wid = gid >> 6, lane = gid & 63;
    if (wid >= n) return;
    float h0 = h[(size_t)wid * 128 + lane];
    float h1 = h[(size_t)wid * 128 + 64 + lane];
    float vs = h0 * a_s[lane] + h1 * a_s[64 + lane];
    float vd = h0 * a_d[lane] + h1 * a_d[64 + lane];
    #pragma unroll
    for (int o = 32; o; o >>= 1) { vs += __shfl_down(vs, o); vd += __shfl_down(vd, o); }
    if (lane == 0) { ssrc[wid] = vs; sdst[wid] = vd; }
}

// ---------------- CSR build (once per call; graph shared by both layers) ----

__global__ void deg_hist(const int* __restrict__ ei, int E, int n, int* __restrict__ deg) {
    int e = blockIdx.x * blockDim.x + threadIdx.x;
    if (e >= E + n) return;
    int d = (e < E) ? ei[E + e] : (e - E);
    atomicAdd(&deg[d], 1);
}

__global__ void scan1(int* __restrict__ deg, int* __restrict__ part, int n) {
    __shared__ int s[256];
    int t = threadIdx.x;
    int i = blockIdx.x * 256 + t;
    int v = (i < n) ? deg[i] : 0;
    s[t] = v; __syncthreads();
    for (int o = 1; o < 256; o <<= 1) {
        int tv = (t >= o) ? s[t - o] : 0;
        __syncthreads();
        s[t] += tv;
        __syncthreads();
    }
    if (i < n) deg[i] = s[t] - v;
    if (t == 255) part[blockIdx.x] = s[255];
}

__global__ void scan2(int* __restrict__ part, int nparts) {
    __shared__ int s[256];
    int t = threadIdx.x;
    int v = (t < nparts) ? part[t] : 0;
    s[t] = v; __syncthreads();
    for (int o = 1; o < 256; o <<= 1) {
        int tv = (t >= o) ? s[t - o] : 0;
        __syncthreads();
        s[t] += tv;
        __syncthreads();
    }
    if (t < nparts) part[t] = s[t] - v;
}

__global__ void scan3(const int* __restrict__ deg, const int* __restrict__ part,
                      int* __restrict__ rowptr, int* __restrict__ cursor, int n, int Etot) {
    int i = blockIdx.x * blockDim.x + threadIdx.x;
    if (i == 0) rowptr[n] = Etot;
    if (i >= n) return;
    int v = deg[i] + part[i >> 8];
    rowptr[i] = v;
    cursor[i] = v;
}

__global__ void edge_scatter(const int* __restrict__ ei, int E, int n,
                             int* __restrict__ cursor, int* __restrict__ csr_src) {
    int e = blockIdx.x * blockDim.x + threadIdx.x;
    if (e >= E + n) return;
    int s, d;
    if (e < E) { s = ei[e]; d = ei[E + e]; } else { s = d = e - E; }
    int p = atomicAdd(&cursor[d], 1);
    csr_src[p] = s;
}

// ------------- fused GAT aggregation: one wave per dst node -----------------
__global__ void gat_gather(const int* __restrict__ rowptr, const int* __restrict__ csr_src,
                           const float* __restrict__ ssrc, const float* __restrict__ sdst,
                           const float* __restrict__ h, const float* __restrict__ bias,
                           float* __restrict__ out, int n) {
    int wid = (blockIdx.x * blockDim.x + threadIdx.x) >> 6;
    int lane = threadIdx.x & 63;
    if (wid >= n) return;
    int beg = rowptr[wid], end = rowptr[wid + 1];
    float sd = sdst[wid];

    float m = -INFINITY;
    for (int base = beg; base < end; base += 64) {
        int i = base + lane;
        float s = -INFINITY;
        if (i < end) {
            float v = ssrc[csr_src[i]] + sd;
            s = v > 0.f ? v : NEG_SLOPE * v;
        }
        m = fmaxf(m, s);
    }
    #pragma unroll
    for (int o = 32; o; o >>= 1) m = fmaxf(m, __shfl_xor(m, o));

    float2 acc = make_float2(0.f, 0.f);
    float den = 0.f;
    for (int base = beg; base < end; base += 64) {
        int i = base + lane;
        int cnt = min(64, end - base);
        int src = 0;
        float w = 0.f;
        if (i < end) {
            src = csr_src[i];
            float v = ssrc[src] + sd;
            v = v > 0.f ? v : NEG_SLOPE * v;
            w = expf(v - m);
        }
        den += w;
        for (int j = 0; j < cnt; ++j) {
            float wj = __shfl(w, j);
            int  sj  = __shfl(src, j);
            float2 hv = ((const float2*)(h + (size_t)sj * 128))[lane];
            acc.x += wj * hv.x;
            acc.y += wj * hv.y;
        }
    }
    #pragma unroll
    for (int o = 32; o; o >>= 1) den += __shfl_xor(den, o);

    float o0 = acc.x / den + bias[2 * lane];
    float o1 = acc.y / den + bias[2 * lane + 1];
    o0 = o0 > 0.f ? o0 : (expf(o0) - 1.f);
    o1 = o1 > 0.f ? o1 : (expf(o1) - 1.f);
    ((float2*)(out + (size_t)wid * 128))[lane] = make_float2(o0, o1);
}

// ---------------- pooling: one block per graph (batch is sorted) ------------
__global__ void pool_graph(const float* __restrict__ y, const int* __restrict__ batch,
                           float* __restrict__ out, int n, int G) {
    int g = blockIdx.x;
    int lo = 0, hi = n;
    while (lo < hi) { int mid = (lo + hi) >> 1; if (batch[mid] < g) lo = mid + 1; else hi = mid; }
    int beg = lo;
    hi = n;
    while (lo < hi) { int mid = (lo + hi) >> 1; if (batch[mid] < g + 1) lo = mid + 1; else hi = mid; }
    int end = lo;

    int c = threadIdx.x & 31;
    int sub = threadIdx.x >> 5;
    float acc = 0.f;
    for (int node = beg + sub; node < end; node += 8)
        acc += y[(size_t)node * 32 + c];

    __shared__ float ls[8][32];
    ls[sub][c] = acc;
    __syncthreads();
    if (sub == 0) {
        float s = 0.f;
        #pragma unroll
        for (int k = 0; k < 8; ++k) s += ls[k][c];
        out[g * 32 + c] = s / fmaxf((float)(end - beg), 1.f);
    }
}

extern "C" void kernel_launch(void* const* d_in, const int* in_sizes, int n_in,
                              void* d_out, int out_size, void* d_ws, size_t ws_size,
                              hipStream_t stream) {
    const float* pos  = (const float*)d_in[0];
    const int*   z    = (const int*)d_in[1];
    const int*   ei   = (const int*)d_in[2];
    const int*   batch= (const int*)d_in[3];
    const float* emb  = (const float*)d_in[4];
    const float* W1   = (const float*)d_in[5];
    const float* a1s  = (const float*)d_in[6];
    const float* a1d  = (const float*)d_in[7];
    const float* b1   = (const float*)d_in[8];
    const float* W2   = (const float*)d_in[9];
    const float* a2s  = (const float*)d_in[10];
    const float* a2d  = (const float*)d_in[11];
    const float* b2   = (const float*)d_in[12];
    const float* Wlin = (const float*)d_in[13];
    const float* blin = (const float*)d_in[14];

    const int N = in_sizes[0] / 3;        // 50000
    const int E = in_sizes[2] / 2;        // 1600000
    const int Etot = E + N;
    const int G = out_size / 32;          // 64

    char* ws = (char*)d_ws;
    size_t NB = (size_t)N * 128 * sizeof(float);
    float* buf0   = (float*)ws;                    // x / h2 / y
    float* buf1   = (float*)(ws + NB);             // h1 / out2
    float* buf2   = (float*)(ws + 2 * NB);         // out1 (=x for layer2)
    float* ssrc   = (float*)(ws + 3 * NB);
    float* sdst   = ssrc + N;
    int*   rowptr = (int*)(sdst + N);              // N+1
    int*   cursor = rowptr + N + 1;                // N
    int*   deg    = cursor + N;                    // N (scan in place)
    int*   part   = deg + N;                       // 256
    int*   csrs   = part + 256;                    // Etot

    const int TB = 256;
    dim3 blk(TB);
    int gElem  = (N * 128 + TB - 1) / TB;
    int gEdge  = (Etot + TB - 1) / TB;
    int gNodeW = ((size_t)N * 64 + TB - 1) / TB;
    int gGemmT = (N + 127) / 128;
    int gGemmO = (N + 63) / 64;
    int nparts = (N + 255) / 256;
    int gGat   = (N + 3) / 4;

    // ---------- CSR build (graph shared by both layers) ----------
    hipMemsetAsync(deg, 0, (size_t)N * sizeof(int), stream);
    deg_hist<<<gEdge, blk, 0, stream>>>(ei, E, N, deg);
    scan1<<<nparts, blk, 0, stream>>>(deg, part, N);
    scan2<<<1, blk, 0, stream>>>(part, nparts);
    scan3<<<nparts, blk, 0, stream>>>(deg, part, rowptr, cursor, N, Etot);
    edge_scatter<<<gEdge, blk, 0, stream>>>(ei, E, N, cursor, csrs);

    // ---------- layer 1 ----------
    build_x<<<gElem, blk, 0, stream>>>(pos, z, emb, buf0, N);
    gemm128_tiled<<<gGemmT, blk, 0, stream>>>(buf0, W1, buf1, N);
    node_dots<<<gNodeW, blk, 0, stream>>>(buf1, a1s, a1d, ssrc, sdst, N);
    gat_gather<<<gGat, blk, 0, stream>>>(rowptr, csrs, ssrc, sdst, buf1, b1, buf2, N);

    // ---------- layer 2 ----------
    gemm128_tiled<<<gGemmT, blk, 0, stream>>>(buf2, W2, buf0, N);
    node_dots<<<gNodeW, blk, 0, stream>>>(buf0, a2s, a2d, ssrc, sdst, N);
    gat_gather<<<gGat, blk, 0, stream>>>(rowptr, csrs, ssrc, sdst, buf0, b2, buf1, N);

    // ---------- linear + pool ----------
    gemm_x128<32, 64><<<gGemmO, blk, 0, stream>>>(buf1, Wlin, blin, buf0, N);
    pool_graph<<<G, blk, 0, stream>>>(buf0, batch, (float*)d_out, N, G);
}

// Round 5
// 600.052 us; speedup vs baseline: 4.0202x; 1.0634x over previous
//
#include <hip/hip_runtime.h>
#include <hip/hip_bf16.h>
#include <math.h>

#define NEG_SLOPE 0.2f

// x[i] = concat(pos[i] (3), emb[z[i]] (125))  -> [N,128]
__global__ void build_x(const float* __restrict__ pos, const int* __restrict__ z,
                        const float* __restrict__ emb, float* __restrict__ x, int n) {
    int id = blockIdx.x * blockDim.x + threadIdx.x;
    if (id >= n * 128) return;
    int node = id >> 7, k = id & 127;
    float v;
    if (k < 3) v = pos[node * 3 + k];
    else       v = emb[z[node] * 125 + (k - 3)];
    x[id] = v;
}

// ---- register-tiled f32 GEMM: Y = X @ W, plus bf16 copy of Y ---------------
__global__ __launch_bounds__(256)
void gemm128_tiled(const float* __restrict__ X, const float* __restrict__ W,
                   float* __restrict__ Y, __hip_bfloat16* __restrict__ Ybf, int n) {
    __shared__ float Xt[32][128];   // [k][row]
    __shared__ float Wl[32][128];   // [k][col]
    int tid = threadIdx.x;
    int tx = tid & 15, ty = tid >> 4;
    int row0 = blockIdx.x * 128;
    float acc[8][8];
    #pragma unroll
    for (int i = 0; i < 8; ++i)
        #pragma unroll
        for (int j = 0; j < 8; ++j) acc[i][j] = 0.f;

    for (int k0 = 0; k0 < 128; k0 += 32) {
        __syncthreads();
        #pragma unroll
        for (int i = 0; i < 4; ++i) {
            int f4 = tid + i * 256;
            int r = f4 >> 3, kp = (f4 & 7) << 2;
            int row = row0 + r;
            float4 v = (row < n) ? *(const float4*)(X + (size_t)row * 128 + k0 + kp)
                                 : make_float4(0.f, 0.f, 0.f, 0.f);
            Xt[kp + 0][r] = v.x; Xt[kp + 1][r] = v.y;
            Xt[kp + 2][r] = v.z; Xt[kp + 3][r] = v.w;
        }
        #pragma unroll
        for (int i = 0; i < 4; ++i) {
            int f4 = tid + i * 256;
            int kr = f4 >> 5, cp = (f4 & 31) << 2;
            *(float4*)(&Wl[kr][cp]) = *(const float4*)(W + (size_t)(k0 + kr) * 128 + cp);
        }
        __syncthreads();
        #pragma unroll 4
        for (int k = 0; k < 32; ++k) {
            float4 xa = *(float4*)(&Xt[k][ty * 8]);
            float4 xb = *(float4*)(&Xt[k][ty * 8 + 4]);
            float4 wa = *(float4*)(&Wl[k][tx * 4]);
            float4 wb = *(float4*)(&Wl[k][64 + tx * 4]);
            float xr[8] = {xa.x, xa.y, xa.z, xa.w, xb.x, xb.y, xb.z, xb.w};
            float wc[8] = {wa.x, wa.y, wa.z, wa.w, wb.x, wb.y, wb.z, wb.w};
            #pragma unroll
            for (int i = 0; i < 8; ++i)
                #pragma unroll
                for (int j = 0; j < 8; ++j) acc[i][j] += xr[i] * wc[j];
        }
    }
    #pragma unroll
    for (int i = 0; i < 8; ++i) {
        int row = row0 + ty * 8 + i;
        if (row >= n) break;
        *(float4*)(Y + (size_t)row * 128 + tx * 4) =
            make_float4(acc[i][0], acc[i][1], acc[i][2], acc[i][3]);
        *(float4*)(Y + (size_t)row * 128 + 64 + tx * 4) =
            make_float4(acc[i][4], acc[i][5], acc[i][6], acc[i][7]);
        ushort4 pa, pb;
        pa.x = __hip_bfloat16_raw(__float2bfloat16(acc[i][0])).x;
        pa.y = __hip_bfloat16_raw(__float2bfloat16(acc[i][1])).x;
        pa.z = __hip_bfloat16_raw(__float2bfloat16(acc[i][2])).x;
        pa.w = __hip_bfloat16_raw(__float2bfloat16(acc[i][3])).x;
        pb.x = __hip_bfloat16_raw(__float2bfloat16(acc[i][4])).x;
        pb.y = __hip_bfloat16_raw(__float2bfloat16(acc[i][5])).x;
        pb.z = __hip_bfloat16_raw(__float2bfloat16(acc[i][6])).x;
        pb.w = __hip_bfloat16_raw(__float2bfloat16(acc[i][7])).x;
        *(ushort4*)((unsigned short*)Ybf + (size_t)row * 128 + tx * 4) = pa;
        *(ushort4*)((unsigned short*)Ybf + (size_t)row * 128 + 64 + tx * 4) = pb;
    }
}

// Y[N,HOUT] = X[N,128] @ W[128,HOUT] (+bias). (final 32-col layer)
template <int HOUT, int ROWS>
__global__ void gemm_x128(const float* __restrict__ X, const float* __restrict__ W,
                          const float* __restrict__ bias, float* __restrict__ Y, int n) {
    __shared__ float Wl[128 * HOUT];
    __shared__ float Xl[ROWS][128];
    for (int i = threadIdx.x; i < 128 * HOUT; i += blockDim.x) Wl[i] = W[i];
    int row0 = blockIdx.x * ROWS;
    for (int i = threadIdx.x; i < ROWS * 128; i += blockDim.x) {
        int r = row0 + (i >> 7);
        Xl[i >> 7][i & 127] = (r < n) ? X[(size_t)r * 128 + (i & 127)] : 0.f;
    }
    __syncthreads();
    const int RPI = 256 / HOUT;
    int lr = threadIdx.x / HOUT;
    int j  = threadIdx.x % HOUT;
    for (int rr = lr; rr < ROWS; rr += RPI) {
        int r = row0 + rr;
        if (r >= n) break;
        float acc = bias ? bias[j] : 0.f;
        #pragma unroll 8
        for (int k = 0; k < 128; ++k) acc += Xl[rr][k] * Wl[k * HOUT + j];
        Y[(size_t)r * HOUT + j] = acc;
    }
}

// ssrc[i] = h[i].a_s ; sdst[i] = h[i].a_d  (one wave per node)
__global__ void node_dots(const float* __restrict__ h, const float* __restrict__ a_s,
                          const float* __restrict__ a_d, float* __restrict__ ssrc,
                          float* __restrict__ sdst, int n) {
    int gid = blockIdx.x * blockDim.x + threadIdx.x;
    int wid = gid >> 6, lane = gid & 63;
    if (wid >= n) return;
    float h0 = h[(size_t)wid * 128 + lane];
    float h1 = h[(size_t)wid * 128 + 64 + lane];
    float vs = h0 * a_s[lane] + h1 * a_s[64 + lane];
    float vd = h0 * a_d[lane] + h1 * a_d[64 + lane];
    #pragma unroll
    for (int o = 32; o; o >>= 1) { vs += __shfl_down(vs, o); vd += __shfl_down(vd, o); }
    if (lane == 0) { ssrc[wid] = vs; sdst[wid] = vd; }
}

// ---------------- CSR build (once per call) ---------------------------------

__global__ void deg_hist(const int* __restrict__ ei, int E, int n, int* __restrict__ deg) {
    int e = blockIdx.x * blockDim.x + threadIdx.x;
    if (e >= E + n) return;
    int d = (e < E) ? ei[E + e] : (e - E);
    atomicAdd(&deg[d], 1);
}

__global__ void scan1(int* __restrict__ deg, int* __restrict__ part, int n) {
    __shared__ int s[256];
    int t = threadIdx.x;
    int i = blockIdx.x * 256 + t;
    int v = (i < n) ? deg[i] : 0;
    s[t] = v; __syncthreads();
    for (int o = 1; o < 256; o <<= 1) {
        int tv = (t >= o) ? s[t - o] : 0;
        __syncthreads();
        s[t] += tv;
        __syncthreads();
    }
    if (i < n) deg[i] = s[t] - v;
    if (t == 255) part[blockIdx.x] = s[255];
}

__global__ void scan2(int* __restrict__ part, int nparts) {
    __shared__ int s[256];
    int t = threadIdx.x;
    int v = (t < nparts) ? part[t] : 0;
    s[t] = v; __syncthreads();
    for (int o = 1; o < 256; o <<= 1) {
        int tv = (t >= o) ? s[t - o] : 0;
        __syncthreads();
        s[t] += tv;
        __syncthreads();
    }
    if (t < nparts) part[t] = s[t] - v;
}

__global__ void scan3(const int* __restrict__ deg, const int* __restrict__ part,
                      int* __restrict__ rowptr, int* __restrict__ cursor, int n, int Etot) {
    int i = blockIdx.x * blockDim.x + threadIdx.x;
    if (i == 0) rowptr[n] = Etot;
    if (i >= n) return;
    int v = deg[i] + part[i >> 8];
    rowptr[i] = v;
    cursor[i] = v;
}

// dst-range-binned scatter: only edges with dst in [dlo,dhi) — writes stay
// in an L2-resident window so lines coalesce before writeback.
__global__ void edge_scatter_binned(const int* __restrict__ ei, int E, int n,
                                    int dlo, int dhi,
                                    int* __restrict__ cursor, int* __restrict__ csr_src) {
    int e = blockIdx.x * blockDim.x + threadIdx.x;
    if (e >= E + n) return;
    int s, d;
    if (e < E) { s = ei[e]; d = ei[E + e]; } else { s = d = e - E; }
    if (d < dlo || d >= dhi) return;
    int p = atomicAdd(&cursor[d], 1);
    csr_src[p] = s;
}

// ------------- fused GAT aggregation: one wave per dst node -----------------
// h features read as bf16 (halves the dominant L2/L3 stream).
__global__ void gat_gather(const int* __restrict__ rowptr, const int* __restrict__ csr_src,
                           const float* __restrict__ ssrc, const float* __restrict__ sdst,
                           const __hip_bfloat16* __restrict__ hb, const float* __restrict__ bias,
                           float* __restrict__ out, int n) {
    int wid = (blockIdx.x * blockDim.x + threadIdx.x) >> 6;
    int lane = threadIdx.x & 63;
    if (wid >= n) return;
    int beg = rowptr[wid], end = rowptr[wid + 1];
    float sd = sdst[wid];
    int deg = end - beg;

    float2 acc = make_float2(0.f, 0.f);
    float den = 0.f;
    const unsigned short* hu = (const unsigned short*)hb;

    if (deg <= 64) {
        // fast path: whole segment resident in one lane-slot each
        int i = beg + lane;
        int src = 0;
        float v = -INFINITY;
        if (i < end) {
            src = csr_src[i];
            float t = ssrc[src] + sd;
            v = t > 0.f ? t : NEG_SLOPE * t;
        }
        float m = v;
        #pragma unroll
        for (int o = 32; o; o >>= 1) m = fmaxf(m, __shfl_xor(m, o));
        float w = (i < end) ? expf(v - m) : 0.f;
        den = w;
        for (int j = 0; j < deg; ++j) {
            float wj = __shfl(w, j);
            int  sj  = __shfl(src, j);
            unsigned hv = *(const unsigned*)(hu + (size_t)sj * 128 + 2 * lane);
            float h0 = __bfloat162float(__hip_bfloat16(__hip_bfloat16_raw{(unsigned short)(hv & 0xffff)}));
            float h1 = __bfloat162float(__hip_bfloat16(__hip_bfloat16_raw{(unsigned short)(hv >> 16)}));
            acc.x += wj * h0;
            acc.y += wj * h1;
        }
    } else {
        float m = -INFINITY;
        for (int base = beg; base < end; base += 64) {
            int i = base + lane;
            float s = -INFINITY;
            if (i < end) {
                float v = ssrc[csr_src[i]] + sd;
                s = v > 0.f ? v : NEG_SLOPE * v;
            }
            m = fmaxf(m, s);
        }
        #pragma unroll
        for (int o = 32; o; o >>= 1) m = fmaxf(m, __shfl_xor(m, o));

        for (int base = beg; base < end; base += 64) {
            int i = base + lane;
            int cnt = min(64, end - base);
            int src = 0;
            float w = 0.f;
            if (i < end) {
                src = csr_src[i];
                float v = ssrc[src] + sd;
                v = v > 0.f ? v : NEG_SLOPE * v;
                w = expf(v - m);
            }
            den += w;
            for (int j = 0; j < cnt; ++j) {
                float wj = __shfl(w, j);
                int  sj  = __shfl(src, j);
                unsigned hv = *(const unsigned*)(hu + (size_t)sj * 128 + 2 * lane);
                float h0 = __bfloat162float(__hip_bfloat16(__hip_bfloat16_raw{(unsigned short)(hv & 0xffff)}));
                float h1 = __bfloat162float(__hip_bfloat16(__hip_bfloat16_raw{(unsigned short)(hv >> 16)}));
                acc.x += wj * h0;
                acc.y += wj * h1;
            }
        }
    }
    #pragma unroll
    for (int o = 32; o; o >>= 1) den += __shfl_xor(den, o);

    float o0 = acc.x / den + bias[2 * lane];
    float o1 = acc.y / den + bias[2 * lane + 1];
    o0 = o0 > 0.f ? o0 : (expf(o0) - 1.f);
    o1 = o1 > 0.f ? o1 : (expf(o1) - 1.f);
    ((float2*)(out + (size_t)wid * 128))[lane] = make_float2(o0, o1);
}

// ---------------- pooling: one block per graph (batch is sorted) ------------
__global__ void pool_graph(const float* __restrict__ y, const int* __restrict__ batch,
                           float* __restrict__ out, int n, int G) {
    int g = blockIdx.x;
    int lo = 0, hi = n;
    while (lo < hi) { int mid = (lo + hi) >> 1; if (batch[mid] < g) lo = mid + 1; else hi = mid; }
    int beg = lo;
    hi = n;
    while (lo < hi) { int mid = (lo + hi) >> 1; if (batch[mid] < g + 1) lo = mid + 1; else hi = mid; }
    int end = lo;

    int c = threadIdx.x & 31;
    int sub = threadIdx.x >> 5;
    float acc = 0.f;
    for (int node = beg + sub; node < end; node += 8)
        acc += y[(size_t)node * 32 + c];

    __shared__ float ls[8][32];
    ls[sub][c] = acc;
    __syncthreads();
    if (sub == 0) {
        float s = 0.f;
        #pragma unroll
        for (int k = 0; k < 8; ++k) s += ls[k][c];
        out[g * 32 + c] = s / fmaxf((float)(end - beg), 1.f);
    }
}

extern "C" void kernel_launch(void* const* d_in, const int* in_sizes, int n_in,
                              void* d_out, int out_size, void* d_ws, size_t ws_size,
                              hipStream_t stream) {
    const float* pos  = (const float*)d_in[0];
    const int*   z    = (const int*)d_in[1];
    const int*   ei   = (const int*)d_in[2];
    const int*   batch= (const int*)d_in[3];
    const float* emb  = (const float*)d_in[4];
    const float* W1   = (const float*)d_in[5];
    const float* a1s  = (const float*)d_in[6];
    const float* a1d  = (const float*)d_in[7];
    const float* b1   = (const float*)d_in[8];
    const float* W2   = (const float*)d_in[9];
    const float* a2s  = (const float*)d_in[10];
    const float* a2d  = (const float*)d_in[11];
    const float* b2   = (const float*)d_in[12];
    const float* Wlin = (const float*)d_in[13];
    const float* blin = (const float*)d_in[14];

    const int N = in_sizes[0] / 3;        // 50000
    const int E = in_sizes[2] / 2;        // 1600000
    const int Etot = E + N;
    const int G = out_size / 32;          // 64

    char* ws = (char*)d_ws;
    size_t NB = (size_t)N * 128 * sizeof(float);
    float* buf0   = (float*)ws;                    // x / h2 / y
    float* buf1   = (float*)(ws + NB);             // h1 / out2
    float* buf2   = (float*)(ws + 2 * NB);         // out1 (=x for layer2)
    float* ssrc   = (float*)(ws + 3 * NB);
    float* sdst   = ssrc + N;
    int*   rowptr = (int*)(sdst + N);              // N+1
    int*   cursor = rowptr + N + 1;                // N
    int*   deg    = cursor + N;                    // N (scan in place)
    int*   part   = deg + N;                       // 256
    int*   csrs   = part + 256;                    // Etot
    __hip_bfloat16* hbf = (__hip_bfloat16*)(csrs + Etot);  // N*128 bf16

    const int TB = 256;
    dim3 blk(TB);
    int gElem  = (N * 128 + TB - 1) / TB;
    int gEdge  = (Etot + TB - 1) / TB;
    int gNodeW = ((size_t)N * 64 + TB - 1) / TB;
    int gGemmT = (N + 127) / 128;
    int gGemmO = (N + 63) / 64;
    int nparts = (N + 255) / 256;
    int gGat   = (N + 3) / 4;

    // ---------- CSR build ----------
    hipMemsetAsync(deg, 0, (size_t)N * sizeof(int), stream);
    deg_hist<<<gEdge, blk, 0, stream>>>(ei, E, N, deg);
    scan1<<<nparts, blk, 0, stream>>>(deg, part, N);
    scan2<<<1, blk, 0, stream>>>(part, nparts);
    scan3<<<nparts, blk, 0, stream>>>(deg, part, rowptr, cursor, N, Etot);
    const int NPASS = 8;
    int binsz = (N + NPASS - 1) / NPASS;
    for (int p = 0; p < NPASS; ++p)
        edge_scatter_binned<<<gEdge, blk, 0, stream>>>(ei, E, N, p * binsz,
                                                       min((p + 1) * binsz, N), cursor, csrs);

    // ---------- layer 1 ----------
    build_x<<<gElem, blk, 0, stream>>>(pos, z, emb, buf0, N);
    gemm128_tiled<<<gGemmT, blk, 0, stream>>>(buf0, W1, buf1, hbf, N);
    node_dots<<<gNodeW, blk, 0, stream>>>(buf1, a1s, a1d, ssrc, sdst, N);
    gat_gather<<<gGat, blk, 0, stream>>>(rowptr, csrs, ssrc, sdst, hbf, b1, buf2, N);

    // ---------- layer 2 ----------
    gemm128_tiled<<<gGemmT, blk, 0, stream>>>(buf2, W2, buf0, hbf, N);
    node_dots<<<gNodeW, blk, 0, stream>>>(buf0, a2s, a2d, ssrc, sdst, N);
    gat_gather<<<gGat, blk, 0, stream>>>(rowptr, csrs, ssrc, sdst, hbf, b2, buf1, N);

    // ---------- linear + pool ----------
    gemm_x128<32, 64><<<gGemmO, blk, 0, stream>>>(buf1, Wlin, blin, buf0, N);
    pool_graph<<<G, blk, 0, stream>>>(buf0, batch, (float*)d_out, N, G);
}

// Round 6
// 583.651 us; speedup vs baseline: 4.1331x; 1.0281x over previous
//
#include <hip/hip_runtime.h>
#include <hip/hip_bf16.h>
#include <math.h>

#define NEG_SLOPE 0.2f
#define SRC_SHIFT 13   // src bucket = src >> 13 (8192 nodes/bucket)

// x[i] = concat(pos[i] (3), emb[z[i]] (125))  -> [N,128]
__global__ void build_x(const float* __restrict__ pos, const int* __restrict__ z,
                        const float* __restrict__ emb, float* __restrict__ x, int n) {
    int id = blockIdx.x * blockDim.x + threadIdx.x;
    if (id >= n * 128) return;
    int node = id >> 7, k = id & 127;
    float v;
    if (k < 3) v = pos[node * 3 + k];
    else       v = emb[z[node] * 125 + (k - 3)];
    x[id] = v;
}

// ---- register-tiled f32 GEMM: Y = X @ W, plus bf16 copy of Y ---------------
__global__ __launch_bounds__(256)
void gemm128_tiled(const float* __restrict__ X, const float* __restrict__ W,
                   float* __restrict__ Y, __hip_bfloat16* __restrict__ Ybf, int n) {
    __shared__ float Xt[32][128];   // [k][row]
    __shared__ float Wl[32][128];   // [k][col]
    int tid = threadIdx.x;
    int tx = tid & 15, ty = tid >> 4;
    int row0 = blockIdx.x * 128;
    float acc[8][8];
    #pragma unroll
    for (int i = 0; i < 8; ++i)
        #pragma unroll
        for (int j = 0; j < 8; ++j) acc[i][j] = 0.f;

    for (int k0 = 0; k0 < 128; k0 += 32) {
        __syncthreads();
        #pragma unroll
        for (int i = 0; i < 4; ++i) {
            int f4 = tid + i * 256;
            int r = f4 >> 3, kp = (f4 & 7) << 2;
            int row = row0 + r;
            float4 v = (row < n) ? *(const float4*)(X + (size_t)row * 128 + k0 + kp)
                                 : make_float4(0.f, 0.f, 0.f, 0.f);
            Xt[kp + 0][r] = v.x; Xt[kp + 1][r] = v.y;
            Xt[kp + 2][r] = v.z; Xt[kp + 3][r] = v.w;
        }
        #pragma unroll
        for (int i = 0; i < 4; ++i) {
            int f4 = tid + i * 256;
            int kr = f4 >> 5, cp = (f4 & 31) << 2;
            *(float4*)(&Wl[kr][cp]) = *(const float4*)(W + (size_t)(k0 + kr) * 128 + cp);
        }
        __syncthreads();
        #pragma unroll 4
        for (int k = 0; k < 32; ++k) {
            float4 xa = *(float4*)(&Xt[k][ty * 8]);
            float4 xb = *(float4*)(&Xt[k][ty * 8 + 4]);
            float4 wa = *(float4*)(&Wl[k][tx * 4]);
            float4 wb = *(float4*)(&Wl[k][64 + tx * 4]);
            float xr[8] = {xa.x, xa.y, xa.z, xa.w, xb.x, xb.y, xb.z, xb.w};
            float wc[8] = {wa.x, wa.y, wa.z, wa.w, wb.x, wb.y, wb.z, wb.w};
            #pragma unroll
            for (int i = 0; i < 8; ++i)
                #pragma unroll
                for (int j = 0; j < 8; ++j) acc[i][j] += xr[i] * wc[j];
        }
    }
    #pragma unroll
    for (int i = 0; i < 8; ++i) {
        int row = row0 + ty * 8 + i;
        if (row >= n) break;
        *(float4*)(Y + (size_t)row * 128 + tx * 4) =
            make_float4(acc[i][0], acc[i][1], acc[i][2], acc[i][3]);
        *(float4*)(Y + (size_t)row * 128 + 64 + tx * 4) =
            make_float4(acc[i][4], acc[i][5], acc[i][6], acc[i][7]);
        ushort4 pa, pb;
        pa.x = __hip_bfloat16_raw(__float2bfloat16(acc[i][0])).x;
        pa.y = __hip_bfloat16_raw(__float2bfloat16(acc[i][1])).x;
        pa.z = __hip_bfloat16_raw(__float2bfloat16(acc[i][2])).x;
        pa.w = __hip_bfloat16_raw(__float2bfloat16(acc[i][3])).x;
        pb.x = __hip_bfloat16_raw(__float2bfloat16(acc[i][4])).x;
        pb.y = __hip_bfloat16_raw(__float2bfloat16(acc[i][5])).x;
        pb.z = __hip_bfloat16_raw(__float2bfloat16(acc[i][6])).x;
        pb.w = __hip_bfloat16_raw(__float2bfloat16(acc[i][7])).x;
        *(ushort4*)((unsigned short*)Ybf + (size_t)row * 128 + tx * 4) = pa;
        *(ushort4*)((unsigned short*)Ybf + (size_t)row * 128 + 64 + tx * 4) = pb;
    }
}

// Y[N,HOUT] = X[N,128] @ W[128,HOUT] (+bias). (final 32-col layer)
template <int HOUT, int ROWS>
__global__ void gemm_x128(const float* __restrict__ X, const float* __restrict__ W,
                          const float* __restrict__ bias, float* __restrict__ Y, int n) {
    __shared__ float Wl[128 * HOUT];
    __shared__ float Xl[ROWS][128];
    for (int i = threadIdx.x; i < 128 * HOUT; i += blockDim.x) Wl[i] = W[i];
    int row0 = blockIdx.x * ROWS;
    for (int i = threadIdx.x; i < ROWS * 128; i += blockDim.x) {
        int r = row0 + (i >> 7);
        Xl[i >> 7][i & 127] = (r < n) ? X[(size_t)r * 128 + (i & 127)] : 0.f;
    }
    __syncthreads();
    const int RPI = 256 / HOUT;
    int lr = threadIdx.x / HOUT;
    int j  = threadIdx.x % HOUT;
    for (int rr = lr; rr < ROWS; rr += RPI) {
        int r = row0 + rr;
        if (r >= n) break;
        float acc = bias ? bias[j] : 0.f;
        #pragma unroll 8
        for (int k = 0; k < 128; ++k) acc += Xl[rr][k] * Wl[k * HOUT + j];
        Y[(size_t)r * HOUT + j] = acc;
    }
}

// ssrc[i] = h[i].a_s ; sdst[i] = h[i].a_d  (one wave per node)
__global__ void node_dots(const float* __restrict__ h, const float* __restrict__ a_s,
                          const float* __restrict__ a_d, float* __restrict__ ssrc,
                          float* __restrict__ sdst, int n) {
    int gid = blockIdx.x * blockDim.x + threadIdx.x;
    int wid = gid >> 6, lane = gid & 63;
    if (wid >= n) return;
    float h0 = h[(size_t)wid * 128 + lane];
    float h1 = h[(size_t)wid * 128 + 64 + lane];
    float vs = h0 * a_s[lane] + h1 * a_s[64 + lane];
    float vd = h0 * a_d[lane] + h1 * a_d[64 + lane];
    #pragma unroll
    for (int o = 32; o; o >>= 1) { vs += __shfl_down(vs, o); vd += __shfl_down(vd, o); }
    if (lane == 0) { ssrc[wid] = vs; sdst[wid] = vd; }
}

// ------- CSR build, src-bucketed rows: counting sort on (dst, src>>13) ------

// cnt[d*B + b] += 1 for each edge
__global__ void hist_db(const int* __restrict__ ei, int E, int n, int B,
                        int* __restrict__ cnt) {
    int e = blockIdx.x * blockDim.x + threadIdx.x;
    if (e >= E + n) return;
    int s, d;
    if (e < E) { s = ei[e]; d = ei[E + e]; } else { s = d = e - E; }
    atomicAdd(&cnt[(size_t)d * B + (s >> SRC_SHIFT)], 1);
}

// in-place per-block exclusive scan; part[b] = block total
__global__ void scan1(int* __restrict__ a, int* __restrict__ part, int n) {
    __shared__ int s[256];
    int t = threadIdx.x;
    int i = blockIdx.x * 256 + t;
    int v = (i < n) ? a[i] : 0;
    s[t] = v; __syncthreads();
    for (int o = 1; o < 256; o <<= 1) {
        int tv = (t >= o) ? s[t - o] : 0;
        __syncthreads();
        s[t] += tv;
        __syncthreads();
    }
    if (i < n) a[i] = s[t] - v;
    if (t == 255) part[blockIdx.x] = s[255];
}

__global__ void scan2(int* __restrict__ part, int nparts) {
    __shared__ int s[256];
    int t = threadIdx.x;
    int v = (t < nparts) ? part[t] : 0;
    s[t] = v; __syncthreads();
    for (int o = 1; o < 256; o <<= 1) {
        int tv = (t >= o) ? s[t - o] : 0;
        __syncthreads();
        s[t] += tv;
        __syncthreads();
    }
    if (t < nparts) part[t] = s[t] - v;
}

__global__ void add_back(int* __restrict__ a, const int* __restrict__ part, int n) {
    int i = blockIdx.x * blockDim.x + threadIdx.x;
    if (i < n) a[i] += part[i >> 8];
}

// rowptr[d] = cnt[d*B] (before cursors are consumed); rowptr[n] = Etot
__global__ void rowptr_from_cnt(const int* __restrict__ cnt, int B,
                                int* __restrict__ rowptr, int n, int Etot) {
    int i = blockIdx.x * blockDim.x + threadIdx.x;
    if (i > n) return;
    rowptr[i] = (i < n) ? cnt[(size_t)i * B] : Etot;
}

// dst-range-binned scatter using per-(d,b) cursors (cnt array consumed in place)
__global__ void edge_scatter_binned(const int* __restrict__ ei, int E, int n,
                                    int dlo, int dhi, int B,
                                    int* __restrict__ cnt, int* __restrict__ csr_src) {
    int e = blockIdx.x * blockDim.x + threadIdx.x;
    if (e >= E + n) return;
    int s, d;
    if (e < E) { s = ei[e]; d = ei[E + e]; } else { s = d = e - E; }
    if (d < dlo || d >= dhi) return;
    int p = atomicAdd(&cnt[(size_t)d * B + (s >> SRC_SHIFT)], 1);
    csr_src[p] = s;
}

// ------------- fused GAT aggregation: one wave per dst node -----------------
// rows are src-bucket-ordered -> concurrent waves sweep a narrow src window.
__global__ void gat_gather(const int* __restrict__ rowptr, const int* __restrict__ csr_src,
                           const float* __restrict__ ssrc, const float* __restrict__ sdst,
                           const __hip_bfloat16* __restrict__ hb, const float* __restrict__ bias,
                           float* __restrict__ out, int n) {
    int wid = (blockIdx.x * blockDim.x + threadIdx.x) >> 6;
    int lane = threadIdx.x & 63;
    if (wid >= n) return;
    int beg = rowptr[wid], end = rowptr[wid + 1];
    float sd = sdst[wid];
    int deg = end - beg;

    float2 acc = make_float2(0.f, 0.f);
    float den = 0.f;
    const unsigned short* hu = (const unsigned short*)hb;

    if (deg <= 64) {
        int i = beg + lane;
        int src = 0;
        float v = -INFINITY;
        if (i < end) {
            src = csr_src[i];
            float t = ssrc[src] + sd;
            v = t > 0.f ? t : NEG_SLOPE * t;
        }
        float m = v;
        #pragma unroll
        for (int o = 32; o; o >>= 1) m = fmaxf(m, __shfl_xor(m, o));
        float w = (i < end) ? expf(v - m) : 0.f;
        den = w;
        for (int j = 0; j < deg; ++j) {
            float wj = __shfl(w, j);
            int  sj  = __shfl(src, j);
            unsigned hv = *(const unsigned*)(hu + (size_t)sj * 128 + 2 * lane);
            float h0 = __bfloat162float(__hip_bfloat16(__hip_bfloat16_raw{(unsigned short)(hv & 0xffff)}));
            float h1 = __bfloat162float(__hip_bfloat16(__hip_bfloat16_raw{(unsigned short)(hv >> 16)}));
            acc.x += wj * h0;
            acc.y += wj * h1;
        }
    } else {
        float m = -INFINITY;
        for (int base = beg; base < end; base += 64) {
            int i = base + lane;
            float s = -INFINITY;
            if (i < end) {
                float v = ssrc[csr_src[i]] + sd;
                s = v > 0.f ? v : NEG_SLOPE * v;
            }
            m = fmaxf(m, s);
        }
        #pragma unroll
        for (int o = 32; o; o >>= 1) m = fmaxf(m, __shfl_xor(m, o));

        for (int base = beg; base < end; base += 64) {
            int i = base + lane;
            int cnt = min(64, end - base);
            int src = 0;
            float w = 0.f;
            if (i < end) {
                src = csr_src[i];
                float v = ssrc[src] + sd;
                v = v > 0.f ? v : NEG_SLOPE * v;
                w = expf(v - m);
            }
            den += w;
            for (int j = 0; j < cnt; ++j) {
                float wj = __shfl(w, j);
                int  sj  = __shfl(src, j);
                unsigned hv = *(const unsigned*)(hu + (size_t)sj * 128 + 2 * lane);
                float h0 = __bfloat162float(__hip_bfloat16(__hip_bfloat16_raw{(unsigned short)(hv & 0xffff)}));
                float h1 = __bfloat162float(__hip_bfloat16(__hip_bfloat16_raw{(unsigned short)(hv >> 16)}));
                acc.x += wj * h0;
                acc.y += wj * h1;
            }
        }
    }
    #pragma unroll
    for (int o = 32; o; o >>= 1) den += __shfl_xor(den, o);

    float o0 = acc.x / den + bias[2 * lane];
    float o1 = acc.y / den + bias[2 * lane + 1];
    o0 = o0 > 0.f ? o0 : (expf(o0) - 1.f);
    o1 = o1 > 0.f ? o1 : (expf(o1) - 1.f);
    ((float2*)(out + (size_t)wid * 128))[lane] = make_float2(o0, o1);
}

// ---------------- pooling: one block per graph (batch is sorted) ------------
__global__ void pool_graph(const float* __restrict__ y, const int* __restrict__ batch,
                           float* __restrict__ out, int n, int G) {
    int g = blockIdx.x;
    int lo = 0, hi = n;
    while (lo < hi) { int mid = (lo + hi) >> 1; if (batch[mid] < g) lo = mid + 1; else hi = mid; }
    int beg = lo;
    hi = n;
    while (lo < hi) { int mid = (lo + hi) >> 1; if (batch[mid] < g + 1) lo = mid + 1; else hi = mid; }
    int end = lo;

    int c = threadIdx.x & 31;
    int sub = threadIdx.x >> 5;
    float acc = 0.f;
    for (int node = beg + sub; node < end; node += 8)
        acc += y[(size_t)node * 32 + c];

    __shared__ float ls[8][32];
    ls[sub][c] = acc;
    __syncthreads();
    if (sub == 0) {
        float s = 0.f;
        #pragma unroll
        for (int k = 0; k < 8; ++k) s += ls[k][c];
        out[g * 32 + c] = s / fmaxf((float)(end - beg), 1.f);
    }
}

extern "C" void kernel_launch(void* const* d_in, const int* in_sizes, int n_in,
                              void* d_out, int out_size, void* d_ws, size_t ws_size,
                              hipStream_t stream) {
    const float* pos  = (const float*)d_in[0];
    const int*   z    = (const int*)d_in[1];
    const int*   ei   = (const int*)d_in[2];
    const int*   batch= (const int*)d_in[3];
    const float* emb  = (const float*)d_in[4];
    const float* W1   = (const float*)d_in[5];
    const float* a1s  = (const float*)d_in[6];
    const float* a1d  = (const float*)d_in[7];
    const float* b1   = (const float*)d_in[8];
    const float* W2   = (const float*)d_in[9];
    const float* a2s  = (const float*)d_in[10];
    const float* a2d  = (const float*)d_in[11];
    const float* b2   = (const float*)d_in[12];
    const float* Wlin = (const float*)d_in[13];
    const float* blin = (const float*)d_in[14];

    const int N = in_sizes[0] / 3;        // 50000
    const int E = in_sizes[2] / 2;        // 1600000
    const int Etot = E + N;
    const int G = out_size / 32;          // 64
    const int B = ((N - 1) >> SRC_SHIFT) + 1;   // src buckets (7 for N=50000)
    const int NBel = N * B;

    char* ws = (char*)d_ws;
    size_t NB = (size_t)N * 128 * sizeof(float);
    float* buf0   = (float*)ws;                    // x / h2 / y
    float* buf1   = (float*)(ws + NB);             // h1 / out2
    float* buf2   = (float*)(ws + 2 * NB);         // out1 (=x for layer2)
    float* ssrc   = (float*)(ws + 3 * NB);
    float* sdst   = ssrc + N;
    int*   rowptr = (int*)(sdst + N);              // N+1
    int*   cnt    = rowptr + N + 1;                // N*B (scan in place -> cursors)
    int*   part1  = cnt + NBel;                    // 2048
    int*   part2  = part1 + 2048;                  // 256
    int*   csrs   = part2 + 256;                   // Etot
    __hip_bfloat16* hbf = (__hip_bfloat16*)(csrs + Etot);  // N*128 bf16

    const int TB = 256;
    dim3 blk(TB);
    int gElem  = (N * 128 + TB - 1) / TB;
    int gEdge  = (Etot + TB - 1) / TB;
    int gNodeW = ((size_t)N * 64 + TB - 1) / TB;
    int gGemmT = (N + 127) / 128;
    int gGemmO = (N + 63) / 64;
    int gGat   = (N + 3) / 4;
    int gScan0 = (NBel + 255) / 256;               // 1368 for N=50000
    int gScan1 = (gScan0 + 255) / 256;             // 6

    // ---------- CSR build: counting sort on (dst, src-bucket) ----------
    hipMemsetAsync(cnt, 0, (size_t)NBel * sizeof(int), stream);
    hist_db<<<gEdge, blk, 0, stream>>>(ei, E, N, B, cnt);
    scan1<<<gScan0, blk, 0, stream>>>(cnt, part1, NBel);
    scan1<<<gScan1, blk, 0, stream>>>(part1, part2, gScan0);
    scan2<<<1, blk, 0, stream>>>(part2, gScan1);
    add_back<<<gScan1, blk, 0, stream>>>(part1, part2, gScan0);
    add_back<<<gScan0, blk, 0, stream>>>(cnt, part1, NBel);
    rowptr_from_cnt<<<(N + 256) / 256, blk, 0, stream>>>(cnt, B, rowptr, N, Etot);
    const int NPASS = 4;
    int binsz = (N + NPASS - 1) / NPASS;
    for (int p = 0; p < NPASS; ++p)
        edge_scatter_binned<<<gEdge, blk, 0, stream>>>(ei, E, N, p * binsz,
                                                       min((p + 1) * binsz, N), B, cnt, csrs);

    // ---------- layer 1 ----------
    build_x<<<gElem, blk, 0, stream>>>(pos, z, emb, buf0, N);
    gemm128_tiled<<<gGemmT, blk, 0, stream>>>(buf0, W1, buf1, hbf, N);
    node_dots<<<gNodeW, blk, 0, stream>>>(buf1, a1s, a1d, ssrc, sdst, N);
    gat_gather<<<gGat, blk, 0, stream>>>(rowptr, csrs, ssrc, sdst, hbf, b1, buf2, N);

    // ---------- layer 2 ----------
    gemm128_tiled<<<gGemmT, blk, 0, stream>>>(buf2, W2, buf0, hbf, N);
    node_dots<<<gNodeW, blk, 0, stream>>>(buf0, a2s, a2d, ssrc, sdst, N);
    gat_gather<<<gGat, blk, 0, stream>>>(rowptr, csrs, ssrc, sdst, hbf, b2, buf1, N);

    // ---------- linear + pool ----------
    gemm_x128<32, 64><<<gGemmO, blk, 0, stream>>>(buf1, Wlin, blin, buf0, N);
    pool_graph<<<G, blk, 0, stream>>>(buf0, batch, (float*)d_out, N, G);
}

// Round 7
// 491.405 us; speedup vs baseline: 4.9090x; 1.1877x over previous
//
#include <hip/hip_runtime.h>
#include <hip/hip_bf16.h>
#include <math.h>

#define NEG_SLOPE 0.2f
#define SRC_SHIFT 13   // src bucket = src >> 13 (8192 nodes/bucket)

__device__ __forceinline__ float bflo(unsigned u) { return __uint_as_float(u << 16); }
__device__ __forceinline__ float bfhi(unsigned u) { return __uint_as_float(u & 0xffff0000u); }

// x[i] = concat(pos[i] (3), emb[z[i]] (125))  -> [N,128]
__global__ void build_x(const float* __restrict__ pos, const int* __restrict__ z,
                        const float* __restrict__ emb, float* __restrict__ x, int n) {
    int id = blockIdx.x * blockDim.x + threadIdx.x;
    if (id >= n * 128) return;
    int node = id >> 7, k = id & 127;
    float v;
    if (k < 3) v = pos[node * 3 + k];
    else       v = emb[z[node] * 125 + (k - 3)];
    x[id] = v;
}

// ---- register-tiled f32 GEMM: Y = X @ W, plus bf16 copy of Y ---------------
__global__ __launch_bounds__(256)
void gemm128_tiled(const float* __restrict__ X, const float* __restrict__ W,
                   float* __restrict__ Y, __hip_bfloat16* __restrict__ Ybf, int n) {
    __shared__ float Xt[32][128];   // [k][row]
    __shared__ float Wl[32][128];   // [k][col]
    int tid = threadIdx.x;
    int tx = tid & 15, ty = tid >> 4;
    int row0 = blockIdx.x * 128;
    float acc[8][8];
    #pragma unroll
    for (int i = 0; i < 8; ++i)
        #pragma unroll
        for (int j = 0; j < 8; ++j) acc[i][j] = 0.f;

    for (int k0 = 0; k0 < 128; k0 += 32) {
        __syncthreads();
        #pragma unroll
        for (int i = 0; i < 4; ++i) {
            int f4 = tid + i * 256;
            int r = f4 >> 3, kp = (f4 & 7) << 2;
            int row = row0 + r;
            float4 v = (row < n) ? *(const float4*)(X + (size_t)row * 128 + k0 + kp)
                                 : make_float4(0.f, 0.f, 0.f, 0.f);
            Xt[kp + 0][r] = v.x; Xt[kp + 1][r] = v.y;
            Xt[kp + 2][r] = v.z; Xt[kp + 3][r] = v.w;
        }
        #pragma unroll
        for (int i = 0; i < 4; ++i) {
            int f4 = tid + i * 256;
            int kr = f4 >> 5, cp = (f4 & 31) << 2;
            *(float4*)(&Wl[kr][cp]) = *(const float4*)(W + (size_t)(k0 + kr) * 128 + cp);
        }
        __syncthreads();
        #pragma unroll 4
        for (int k = 0; k < 32; ++k) {
            float4 xa = *(float4*)(&Xt[k][ty * 8]);
            float4 xb = *(float4*)(&Xt[k][ty * 8 + 4]);
            float4 wa = *(float4*)(&Wl[k][tx * 4]);
            float4 wb = *(float4*)(&Wl[k][64 + tx * 4]);
            float xr[8] = {xa.x, xa.y, xa.z, xa.w, xb.x, xb.y, xb.z, xb.w};
            float wc[8] = {wa.x, wa.y, wa.z, wa.w, wb.x, wb.y, wb.z, wb.w};
            #pragma unroll
            for (int i = 0; i < 8; ++i)
                #pragma unroll
                for (int j = 0; j < 8; ++j) acc[i][j] += xr[i] * wc[j];
        }
    }
    #pragma unroll
    for (int i = 0; i < 8; ++i) {
        int row = row0 + ty * 8 + i;
        if (row >= n) break;
        *(float4*)(Y + (size_t)row * 128 + tx * 4) =
            make_float4(acc[i][0], acc[i][1], acc[i][2], acc[i][3]);
        *(float4*)(Y + (size_t)row * 128 + 64 + tx * 4) =
            make_float4(acc[i][4], acc[i][5], acc[i][6], acc[i][7]);
        ushort4 pa, pb;
        pa.x = __hip_bfloat16_raw(__float2bfloat16(acc[i][0])).x;
        pa.y = __hip_bfloat16_raw(__float2bfloat16(acc[i][1])).x;
        pa.z = __hip_bfloat16_raw(__float2bfloat16(acc[i][2])).x;
        pa.w = __hip_bfloat16_raw(__float2bfloat16(acc[i][3])).x;
        pb.x = __hip_bfloat16_raw(__float2bfloat16(acc[i][4])).x;
        pb.y = __hip_bfloat16_raw(__float2bfloat16(acc[i][5])).x;
        pb.z = __hip_bfloat16_raw(__float2bfloat16(acc[i][6])).x;
        pb.w = __hip_bfloat16_raw(__float2bfloat16(acc[i][7])).x;
        *(ushort4*)((unsigned short*)Ybf + (size_t)row * 128 + tx * 4) = pa;
        *(ushort4*)((unsigned short*)Ybf + (size_t)row * 128 + 64 + tx * 4) = pb;
    }
}

// Y[N,HOUT] = X[N,128] @ W[128,HOUT] (+bias). (final 32-col layer)
template <int HOUT, int ROWS>
__global__ void gemm_x128(const float* __restrict__ X, const float* __restrict__ W,
                          const float* __restrict__ bias, float* __restrict__ Y, int n) {
    __shared__ float Wl[128 * HOUT];
    __shared__ float Xl[ROWS][128];
    for (int i = threadIdx.x; i < 128 * HOUT; i += blockDim.x) Wl[i] = W[i];
    int row0 = blockIdx.x * ROWS;
    for (int i = threadIdx.x; i < ROWS * 128; i += blockDim.x) {
        int r = row0 + (i >> 7);
        Xl[i >> 7][i & 127] = (r < n) ? X[(size_t)r * 128 + (i & 127)] : 0.f;
    }
    __syncthreads();
    const int RPI = 256 / HOUT;
    int lr = threadIdx.x / HOUT;
    int j  = threadIdx.x % HOUT;
    for (int rr = lr; rr < ROWS; rr += RPI) {
        int r = row0 + rr;
        if (r >= n) break;
        float acc = bias ? bias[j] : 0.f;
        #pragma unroll 8
        for (int k = 0; k < 128; ++k) acc += Xl[rr][k] * Wl[k * HOUT + j];
        Y[(size_t)r * HOUT + j] = acc;
    }
}

// ssrc[i] = h[i].a_s ; sdst[i] = h[i].a_d  (one wave per node)
__global__ void node_dots(const float* __restrict__ h, const float* __restrict__ a_s,
                          const float* __restrict__ a_d, float* __restrict__ ssrc,
                          float* __restrict__ sdst, int n) {
    int gid = blockIdx.x * blockDim.x + threadIdx.x;
    int wid = gid >> 6, lane = gid & 63;
    if (wid >= n) return;
    float h0 = h[(size_t)wid * 128 + lane];
    float h1 = h[(size_t)wid * 128 + 64 + lane];
    float vs = h0 * a_s[lane] + h1 * a_s[64 + lane];
    float vd = h0 * a_d[lane] + h1 * a_d[64 + lane];
    #pragma unroll
    for (int o = 32; o; o >>= 1) { vs += __shfl_down(vs, o); vd += __shfl_down(vd, o); }
    if (lane == 0) { ssrc[wid] = vs; sdst[wid] = vd; }
}

// ------- CSR build, src-bucketed rows: counting sort on (dst, src>>13) ------

__global__ void hist_db(const int* __restrict__ ei, int E, int n, int B,
                        int* __restrict__ cnt) {
    int e = blockIdx.x * blockDim.x + threadIdx.x;
    if (e >= E + n) return;
    int s, d;
    if (e < E) { s = ei[e]; d = ei[E + e]; } else { s = d = e - E; }
    atomicAdd(&cnt[(size_t)d * B + (s >> SRC_SHIFT)], 1);
}

__global__ void scan1(int* __restrict__ a, int* __restrict__ part, int n) {
    __shared__ int s[256];
    int t = threadIdx.x;
    int i = blockIdx.x * 256 + t;
    int v = (i < n) ? a[i] : 0;
    s[t] = v; __syncthreads();
    for (int o = 1; o < 256; o <<= 1) {
        int tv = (t >= o) ? s[t - o] : 0;
        __syncthreads();
        s[t] += tv;
        __syncthreads();
    }
    if (i < n) a[i] = s[t] - v;
    if (t == 255) part[blockIdx.x] = s[255];
}

__global__ void scan2(int* __restrict__ part, int nparts) {
    __shared__ int s[256];
    int t = threadIdx.x;
    int v = (t < nparts) ? part[t] : 0;
    s[t] = v; __syncthreads();
    for (int o = 1; o < 256; o <<= 1) {
        int tv = (t >= o) ? s[t - o] : 0;
        __syncthreads();
        s[t] += tv;
        __syncthreads();
    }
    if (t < nparts) part[t] = s[t] - v;
}

__global__ void add_back(int* __restrict__ a, const int* __restrict__ part, int n) {
    int i = blockIdx.x * blockDim.x + threadIdx.x;
    if (i < n) a[i] += part[i >> 8];
}

__global__ void rowptr_from_cnt(const int* __restrict__ cnt, int B,
                                int* __restrict__ rowptr, int n, int Etot) {
    int i = blockIdx.x * blockDim.x + threadIdx.x;
    if (i > n) return;
    rowptr[i] = (i < n) ? cnt[(size_t)i * B] : Etot;
}

__global__ void edge_scatter_binned(const int* __restrict__ ei, int E, int n,
                                    int dlo, int dhi, int B,
                                    int* __restrict__ cnt, int* __restrict__ csr_src) {
    int e = blockIdx.x * blockDim.x + threadIdx.x;
    if (e >= E + n) return;
    int s, d;
    if (e < E) { s = ei[e]; d = ei[E + e]; } else { s = d = e - E; }
    if (d < dlo || d >= dhi) return;
    int p = atomicAdd(&cnt[(size_t)d * B + (s >> SRC_SHIFT)], 1);
    csr_src[p] = s;
}

// ------------- fused GAT aggregation: one wave per dst node -----------------
// lane = 16*g + c: subgroup g in [0,4) walks edges, chunk c in [0,16) covers
// 8 bf16 feats via one uint4 -> 4 independent 256B row-reads in flight/wave.
__global__ void gat_gather(const int* __restrict__ rowptr, const int* __restrict__ csr_src,
                           const float* __restrict__ ssrc, const float* __restrict__ sdst,
                           const __hip_bfloat16* __restrict__ hb, const float* __restrict__ bias,
                           float* __restrict__ out, int n) {
    int wid = (blockIdx.x * blockDim.x + threadIdx.x) >> 6;
    int lane = threadIdx.x & 63;
    if (wid >= n) return;
    int beg = rowptr[wid], end = rowptr[wid + 1];
    float sd = sdst[wid];
    int g = lane >> 4;
    int c = lane & 15;
    const unsigned short* hu = (const unsigned short*)hb;

    // ---- scores for first chunk (kept in regs), max over all chunks ----
    int src0 = 0; float v0 = -INFINITY;
    {
        int i = beg + lane;
        if (i < end) {
            src0 = csr_src[i];
            float t = ssrc[src0] + sd;
            v0 = t > 0.f ? t : NEG_SLOPE * t;
        }
    }
    float m = v0;
    for (int base = beg + 64; base < end; base += 64) {
        int i = base + lane;
        float s = -INFINITY;
        if (i < end) {
            float t = ssrc[csr_src[i]] + sd;
            s = t > 0.f ? t : NEG_SLOPE * t;
        }
        m = fmaxf(m, s);
    }
    #pragma unroll
    for (int o = 32; o; o >>= 1) m = fmaxf(m, __shfl_xor(m, o));

    // ---- accumulate: 4 edges in parallel, 8 feats/lane ----
    float acc[8];
    #pragma unroll
    for (int k = 0; k < 8; ++k) acc[k] = 0.f;
    float den = 0.f;

    for (int base = beg; base < end; base += 64) {
        int cnt = min(64, end - base);
        int src; float w;
        if (base == beg) {
            src = src0;
            w = (lane < cnt) ? expf(v0 - m) : 0.f;
        } else {
            int i = base + lane;
            src = 0; w = 0.f;
            if (i < end) {
                src = csr_src[i];
                float t = ssrc[src] + sd;
                t = t > 0.f ? t : NEG_SLOPE * t;
                w = expf(t - m);
            }
        }
        den += w;
        int steps = (cnt + 3) >> 2;
        for (int j = 0; j < steps; ++j) {
            int e = j * 4 + g;
            int idx = min(e, cnt - 1);
            float wj = __shfl(w, idx);
            int  sj  = __shfl(src, idx);
            if (e >= cnt) wj = 0.f;
            uint4 hv = ((const uint4*)(hu + (size_t)sj * 128))[c];
            acc[0] += wj * bflo(hv.x); acc[1] += wj * bfhi(hv.x);
            acc[2] += wj * bflo(hv.y); acc[3] += wj * bfhi(hv.y);
            acc[4] += wj * bflo(hv.z); acc[5] += wj * bfhi(hv.z);
            acc[6] += wj * bflo(hv.w); acc[7] += wj * bfhi(hv.w);
        }
    }
    #pragma unroll
    for (int o = 32; o; o >>= 1) den += __shfl_xor(den, o);
    #pragma unroll
    for (int k = 0; k < 8; ++k) {
        acc[k] += __shfl_xor(acc[k], 16);
        acc[k] += __shfl_xor(acc[k], 32);
    }
    if (g == 0) {
        float o8[8];
        #pragma unroll
        for (int k = 0; k < 8; ++k) {
            float v = acc[k] / den + bias[c * 8 + k];
            o8[k] = v > 0.f ? v : (expf(v) - 1.f);
        }
        float* op = out + (size_t)wid * 128 + c * 8;
        *(float4*)op       = make_float4(o8[0], o8[1], o8[2], o8[3]);
        *(float4*)(op + 4) = make_float4(o8[4], o8[5], o8[6], o8[7]);
    }
}

// ---------------- pooling: one block per graph (batch is sorted) ------------
__global__ void pool_graph(const float* __restrict__ y, const int* __restrict__ batch,
                           float* __restrict__ out, int n, int G) {
    int g = blockIdx.x;
    int lo = 0, hi = n;
    while (lo < hi) { int mid = (lo + hi) >> 1; if (batch[mid] < g) lo = mid + 1; else hi = mid; }
    int beg = lo;
    hi = n;
    while (lo < hi) { int mid = (lo + hi) >> 1; if (batch[mid] < g + 1) lo = mid + 1; else hi = mid; }
    int end = lo;

    int c = threadIdx.x & 31;
    int sub = threadIdx.x >> 5;
    float acc = 0.f;
    for (int node = beg + sub; node < end; node += 8)
        acc += y[(size_t)node * 32 + c];

    __shared__ float ls[8][32];
    ls[sub][c] = acc;
    __syncthreads();
    if (sub == 0) {
        float s = 0.f;
        #pragma unroll
        for (int k = 0; k < 8; ++k) s += ls[k][c];
        out[g * 32 + c] = s / fmaxf((float)(end - beg), 1.f);
    }
}

extern "C" void kernel_launch(void* const* d_in, const int* in_sizes, int n_in,
                              void* d_out, int out_size, void* d_ws, size_t ws_size,
                              hipStream_t stream) {
    const float* pos  = (const float*)d_in[0];
    const int*   z    = (const int*)d_in[1];
    const int*   ei   = (const int*)d_in[2];
    const int*   batch= (const int*)d_in[3];
    const float* emb  = (const float*)d_in[4];
    const float* W1   = (const float*)d_in[5];
    const float* a1s  = (const float*)d_in[6];
    const float* a1d  = (const float*)d_in[7];
    const float* b1   = (const float*)d_in[8];
    const float* W2   = (const float*)d_in[9];
    const float* a2s  = (const float*)d_in[10];
    const float* a2d  = (const float*)d_in[11];
    const float* b2   = (const float*)d_in[12];
    const float* Wlin = (const float*)d_in[13];
    const float* blin = (const float*)d_in[14];

    const int N = in_sizes[0] / 3;        // 50000
    const int E = in_sizes[2] / 2;        // 1600000
    const int Etot = E + N;
    const int G = out_size / 32;          // 64
    const int B = ((N - 1) >> SRC_SHIFT) + 1;   // src buckets (7 for N=50000)
    const int NBel = N * B;

    char* ws = (char*)d_ws;
    size_t NB = (size_t)N * 128 * sizeof(float);
    float* buf0   = (float*)ws;                    // x / h2 / y
    float* buf1   = (float*)(ws + NB);             // h1 / out2
    float* buf2   = (float*)(ws + 2 * NB);         // out1 (=x for layer2)
    float* ssrc   = (float*)(ws + 3 * NB);
    float* sdst   = ssrc + N;
    int*   rowptr = (int*)(sdst + N);              // N+1
    int*   cnt    = rowptr + N + 1;                // N*B (scan in place -> cursors)
    int*   part1  = cnt + NBel;                    // 2048
    int*   part2  = part1 + 2048;                  // 256
    int*   csrs   = part2 + 256;                   // Etot
    uintptr_t hp  = (uintptr_t)(csrs + Etot);
    hp = (hp + 255) & ~(uintptr_t)255;             // 256B-align for uint4 rows
    __hip_bfloat16* hbf = (__hip_bfloat16*)hp;     // N*128 bf16

    const int TB = 256;
    dim3 blk(TB);
    int gElem  = (N * 128 + TB - 1) / TB;
    int gEdge  = (Etot + TB - 1) / TB;
    int gNodeW = ((size_t)N * 64 + TB - 1) / TB;
    int gGemmT = (N + 127) / 128;
    int gGemmO = (N + 63) / 64;
    int gGat   = (N + 3) / 4;
    int gScan0 = (NBel + 255) / 256;
    int gScan1 = (gScan0 + 255) / 256;

    // ---------- CSR build: counting sort on (dst, src-bucket) ----------
    hipMemsetAsync(cnt, 0, (size_t)NBel * sizeof(int), stream);
    hist_db<<<gEdge, blk, 0, stream>>>(ei, E, N, B, cnt);
    scan1<<<gScan0, blk, 0, stream>>>(cnt, part1, NBel);
    scan1<<<gScan1, blk, 0, stream>>>(part1, part2, gScan0);
    scan2<<<1, blk, 0, stream>>>(part2, gScan1);
    add_back<<<gScan1, blk, 0, stream>>>(part1, part2, gScan0);
    add_back<<<gScan0, blk, 0, stream>>>(cnt, part1, NBel);
    rowptr_from_cnt<<<(N + 256) / 256, blk, 0, stream>>>(cnt, B, rowptr, N, Etot);
    const int NPASS = 4;
    int binsz = (N + NPASS - 1) / NPASS;
    for (int p = 0; p < NPASS; ++p)
        edge_scatter_binned<<<gEdge, blk, 0, stream>>>(ei, E, N, p * binsz,
                                                       min((p + 1) * binsz, N), B, cnt, csrs);

    // ---------- layer 1 ----------
    build_x<<<gElem, blk, 0, stream>>>(pos, z, emb, buf0, N);
    gemm128_tiled<<<gGemmT, blk, 0, stream>>>(buf0, W1, buf1, hbf, N);
    node_dots<<<gNodeW, blk, 0, stream>>>(buf1, a1s, a1d, ssrc, sdst, N);
    gat_gather<<<gGat, blk, 0, stream>>>(rowptr, csrs, ssrc, sdst, hbf, b1, buf2, N);

    // ---------- layer 2 ----------
    gemm128_tiled<<<gGemmT, blk, 0, stream>>>(buf2, W2, buf0, hbf, N);
    node_dots<<<gNodeW, blk, 0, stream>>>(buf0, a2s, a2d, ssrc, sdst, N);
    gat_gather<<<gGat, blk, 0, stream>>>(rowptr, csrs, ssrc, sdst, hbf, b2, buf1, N);

    // ---------- linear + pool ----------
    gemm_x128<32, 64><<<gGemmO, blk, 0, stream>>>(buf1, Wlin, blin, buf0, N);
    pool_graph<<<G, blk, 0, stream>>>(buf0, batch, (float*)d_out, N, G);
}

// Round 8
// 378.864 us; speedup vs baseline: 6.3672x; 1.2970x over previous
//
#include <hip/hip_runtime.h>
#include <hip/hip_bf16.h>
#include <math.h>

#define NEG_SLOPE 0.2f
#define BIN_SHIFT 8          // dst bin = dst >> 8  (196 bins for N=50000)
#define CHUNK 8192           // edges per block in bin_hist / bin_scatter

__device__ __forceinline__ float bflo(unsigned u) { return __uint_as_float(u << 16); }
__device__ __forceinline__ float bfhi(unsigned u) { return __uint_as_float(u & 0xffff0000u); }

// x[i] = concat(pos[i] (3), emb[z[i]] (125))  -> [N,128]
__global__ void build_x(const float* __restrict__ pos, const int* __restrict__ z,
                        const float* __restrict__ emb, float* __restrict__ x, int n) {
    int id = blockIdx.x * blockDim.x + threadIdx.x;
    if (id >= n * 128) return;
    int node = id >> 7, k = id & 127;
    float v;
    if (k < 3) v = pos[node * 3 + k];
    else       v = emb[z[node] * 125 + (k - 3)];
    x[id] = v;
}

// ---- register-tiled f32 GEMM: Y = X @ W, plus bf16 copy of Y ---------------
__global__ __launch_bounds__(256)
void gemm128_tiled(const float* __restrict__ X, const float* __restrict__ W,
                   float* __restrict__ Y, __hip_bfloat16* __restrict__ Ybf, int n) {
    __shared__ float Xt[32][128];   // [k][row]
    __shared__ float Wl[32][128];   // [k][col]
    int tid = threadIdx.x;
    int tx = tid & 15, ty = tid >> 4;
    int row0 = blockIdx.x * 128;
    float acc[8][8];
    #pragma unroll
    for (int i = 0; i < 8; ++i)
        #pragma unroll
        for (int j = 0; j < 8; ++j) acc[i][j] = 0.f;

    for (int k0 = 0; k0 < 128; k0 += 32) {
        __syncthreads();
        #pragma unroll
        for (int i = 0; i < 4; ++i) {
            int f4 = tid + i * 256;
            int r = f4 >> 3, kp = (f4 & 7) << 2;
            int row = row0 + r;
            float4 v = (row < n) ? *(const float4*)(X + (size_t)row * 128 + k0 + kp)
                                 : make_float4(0.f, 0.f, 0.f, 0.f);
            Xt[kp + 0][r] = v.x; Xt[kp + 1][r] = v.y;
            Xt[kp + 2][r] = v.z; Xt[kp + 3][r] = v.w;
        }
        #pragma unroll
        for (int i = 0; i < 4; ++i) {
            int f4 = tid + i * 256;
            int kr = f4 >> 5, cp = (f4 & 31) << 2;
            *(float4*)(&Wl[kr][cp]) = *(const float4*)(W + (size_t)(k0 + kr) * 128 + cp);
        }
        __syncthreads();
        #pragma unroll 4
        for (int k = 0; k < 32; ++k) {
            float4 xa = *(float4*)(&Xt[k][ty * 8]);
            float4 xb = *(float4*)(&Xt[k][ty * 8 + 4]);
            float4 wa = *(float4*)(&Wl[k][tx * 4]);
            float4 wb = *(float4*)(&Wl[k][64 + tx * 4]);
            float xr[8] = {xa.x, xa.y, xa.z, xa.w, xb.x, xb.y, xb.z, xb.w};
            float wc[8] = {wa.x, wa.y, wa.z, wa.w, wb.x, wb.y, wb.z, wb.w};
            #pragma unroll
            for (int i = 0; i < 8; ++i)
                #pragma unroll
                for (int j = 0; j < 8; ++j) acc[i][j] += xr[i] * wc[j];
        }
    }
    #pragma unroll
    for (int i = 0; i < 8; ++i) {
        int row = row0 + ty * 8 + i;
        if (row >= n) break;
        *(float4*)(Y + (size_t)row * 128 + tx * 4) =
            make_float4(acc[i][0], acc[i][1], acc[i][2], acc[i][3]);
        *(float4*)(Y + (size_t)row * 128 + 64 + tx * 4) =
            make_float4(acc[i][4], acc[i][5], acc[i][6], acc[i][7]);
        ushort4 pa, pb;
        pa.x = __hip_bfloat16_raw(__float2bfloat16(acc[i][0])).x;
        pa.y = __hip_bfloat16_raw(__float2bfloat16(acc[i][1])).x;
        pa.z = __hip_bfloat16_raw(__float2bfloat16(acc[i][2])).x;
        pa.w = __hip_bfloat16_raw(__float2bfloat16(acc[i][3])).x;
        pb.x = __hip_bfloat16_raw(__float2bfloat16(acc[i][4])).x;
        pb.y = __hip_bfloat16_raw(__float2bfloat16(acc[i][5])).x;
        pb.z = __hip_bfloat16_raw(__float2bfloat16(acc[i][6])).x;
        pb.w = __hip_bfloat16_raw(__float2bfloat16(acc[i][7])).x;
        *(ushort4*)((unsigned short*)Ybf + (size_t)row * 128 + tx * 4) = pa;
        *(ushort4*)((unsigned short*)Ybf + (size_t)row * 128 + 64 + tx * 4) = pb;
    }
}

// Y[N,HOUT] = X[N,128] @ W[128,HOUT] (+bias). (final 32-col layer)
template <int HOUT, int ROWS>
__global__ void gemm_x128(const float* __restrict__ X, const float* __restrict__ W,
                          const float* __restrict__ bias, float* __restrict__ Y, int n) {
    __shared__ float Wl[128 * HOUT];
    __shared__ float Xl[ROWS][128];
    for (int i = threadIdx.x; i < 128 * HOUT; i += blockDim.x) Wl[i] = W[i];
    int row0 = blockIdx.x * ROWS;
    for (int i = threadIdx.x; i < ROWS * 128; i += blockDim.x) {
        int r = row0 + (i >> 7);
        Xl[i >> 7][i & 127] = (r < n) ? X[(size_t)r * 128 + (i & 127)] : 0.f;
    }
    __syncthreads();
    const int RPI = 256 / HOUT;
    int lr = threadIdx.x / HOUT;
    int j  = threadIdx.x % HOUT;
    for (int rr = lr; rr < ROWS; rr += RPI) {
        int r = row0 + rr;
        if (r >= n) break;
        float acc = bias ? bias[j] : 0.f;
        #pragma unroll 8
        for (int k = 0; k < 128; ++k) acc += Xl[rr][k] * Wl[k * HOUT + j];
        Y[(size_t)r * HOUT + j] = acc;
    }
}

// ssrc[i] = h[i].a_s ; sdst[i] = h[i].a_d  (one wave per node)
__global__ void node_dots(const float* __restrict__ h, const float* __restrict__ a_s,
                          const float* __restrict__ a_d, float* __restrict__ ssrc,
                          float* __restrict__ sdst, int n) {
    int gid = blockIdx.x * blockDim.x + threadIdx.x;
    int wid = gid >> 6, lane = gid & 63;
    if (wid >= n) return;
    float h0 = h[(size_t)wid * 128 + lane];
    float h1 = h[(size_t)wid * 128 + 64 + lane];
    float vs = h0 * a_s[lane] + h1 * a_s[64 + lane];
    float vd = h0 * a_d[lane] + h1 * a_d[64 + lane];
    #pragma unroll
    for (int o = 32; o; o >>= 1) { vs += __shfl_down(vs, o); vd += __shfl_down(vd, o); }
    if (lane == 0) { ssrc[wid] = vs; sdst[wid] = vd; }
}

// ------------- CSR build: two-level dst binning (no global hist atomics) ----

// K1: LDS-privatized coarse histogram (bin = dst>>8)
__global__ void bin_hist(const int* __restrict__ ei, int E, int n, int nbins,
                         int* __restrict__ binCnt) {
    __shared__ int h[256];
    int t = threadIdx.x;
    h[t] = 0;
    __syncthreads();
    int lo = blockIdx.x * CHUNK, hi = min(lo + CHUNK, E + n);
    for (int e = lo + t; e < hi; e += 256) {
        int d = (e < E) ? ei[E + e] : (e - E);
        atomicAdd(&h[d >> BIN_SHIFT], 1);
    }
    __syncthreads();
    if (t < nbins && h[t]) atomicAdd(&binCnt[t], h[t]);
}

// K2: exclusive scan over nbins (<=256), init cursors, rowptr[n]=Etot
__global__ void bin_scan(const int* __restrict__ binCnt, int nbins,
                         int* __restrict__ binBase, int* __restrict__ binCursor,
                         int* __restrict__ rowptr, int n, int Etot) {
    __shared__ int s[256];
    int t = threadIdx.x;
    int v = (t < nbins) ? binCnt[t] : 0;
    s[t] = v; __syncthreads();
    for (int o = 1; o < 256; o <<= 1) {
        int tv = (t >= o) ? s[t - o] : 0;
        __syncthreads();
        s[t] += tv;
        __syncthreads();
    }
    if (t < nbins) { binBase[t] = s[t] - v; binCursor[t] = s[t] - v; }
    if (t == 0) { binBase[nbins] = Etot; rowptr[n] = Etot; }
}

// K3: per-block LDS hist -> one reservation atomic per (block,bin) -> place pairs
__global__ void bin_scatter(const int* __restrict__ ei, int E, int n, int nbins,
                            int* __restrict__ binCursor, uint2* __restrict__ pairs) {
    __shared__ int h[256], cur[256];
    int t = threadIdx.x;
    h[t] = 0;
    __syncthreads();
    int lo = blockIdx.x * CHUNK, hi = min(lo + CHUNK, E + n);
    for (int e = lo + t; e < hi; e += 256) {
        int d = (e < E) ? ei[E + e] : (e - E);
        atomicAdd(&h[d >> BIN_SHIFT], 1);
    }
    __syncthreads();
    if (t < nbins) cur[t] = h[t] ? atomicAdd(&binCursor[t], h[t]) : 0;
    __syncthreads();
    for (int e = lo + t; e < hi; e += 256) {
        int s, d;
        if (e < E) { s = ei[e]; d = ei[E + e]; } else { s = d = e - E; }
        int p = atomicAdd(&cur[d >> BIN_SHIFT], 1);
        pairs[p] = make_uint2((unsigned)s, (unsigned)d);
    }
}

// K4: one block per bin: local hist over 256 dsts -> rowptr + final CSR scatter
__global__ void bin_finalize(const uint2* __restrict__ pairs, const int* __restrict__ binBase,
                             int* __restrict__ rowptr, int* __restrict__ csr_src, int n) {
    int b = blockIdx.x;
    int lo = binBase[b], hi = binBase[b + 1];
    int d0 = b << BIN_SHIFT;
    int nd = min(256, n - d0);
    __shared__ int h[256], s[256], cur[256];
    int t = threadIdx.x;
    h[t] = 0;
    __syncthreads();
    for (int i = lo + t; i < hi; i += 256)
        atomicAdd(&h[pairs[i].y - d0], 1);
    __syncthreads();
    int v = h[t];
    s[t] = v; __syncthreads();
    for (int o = 1; o < 256; o <<= 1) {
        int tv = (t >= o) ? s[t - o] : 0;
        __syncthreads();
        s[t] += tv;
        __syncthreads();
    }
    int excl = lo + s[t] - v;
    if (t < nd) rowptr[d0 + t] = excl;
    cur[t] = excl;
    __syncthreads();
    for (int i = lo + t; i < hi; i += 256) {
        uint2 pr = pairs[i];
        int p = atomicAdd(&cur[pr.y - d0], 1);
        csr_src[p] = (int)pr.x;
    }
}

// ------------- fused GAT aggregation: one wave per dst node -----------------
// lane = 16*g + c: subgroup g in [0,4) walks edges, chunk c in [0,16) covers
// 8 bf16 feats via one uint4 -> 4 independent 256B row-reads in flight/wave.
__global__ void gat_gather(const int* __restrict__ rowptr, const int* __restrict__ csr_src,
                           const float* __restrict__ ssrc, const float* __restrict__ sdst,
                           const __hip_bfloat16* __restrict__ hb, const float* __restrict__ bias,
                           float* __restrict__ out, int n) {
    int wid = (blockIdx.x * blockDim.x + threadIdx.x) >> 6;
    int lane = threadIdx.x & 63;
    if (wid >= n) return;
    int beg = rowptr[wid], end = rowptr[wid + 1];
    float sd = sdst[wid];
    int g = lane >> 4;
    int c = lane & 15;
    const unsigned short* hu = (const unsigned short*)hb;

    int src0 = 0; float v0 = -INFINITY;
    {
        int i = beg + lane;
        if (i < end) {
            src0 = csr_src[i];
            float t = ssrc[src0] + sd;
            v0 = t > 0.f ? t : NEG_SLOPE * t;
        }
    }
    float m = v0;
    for (int base = beg + 64; base < end; base += 64) {
        int i = base + lane;
        float s = -INFINITY;
        if (i < end) {
            float t = ssrc[csr_src[i]] + sd;
            s = t > 0.f ? t : NEG_SLOPE * t;
        }
        m = fmaxf(m, s);
    }
    #pragma unroll
    for (int o = 32; o; o >>= 1) m = fmaxf(m, __shfl_xor(m, o));

    float acc[8];
    #pragma unroll
    for (int k = 0; k < 8; ++k) acc[k] = 0.f;
    float den = 0.f;

    for (int base = beg; base < end; base += 64) {
        int cnt = min(64, end - base);
        int src; float w;
        if (base == beg) {
            src = src0;
            w = (lane < cnt) ? expf(v0 - m) : 0.f;
        } else {
            int i = base + lane;
            src = 0; w = 0.f;
            if (i < end) {
                src = csr_src[i];
                float t = ssrc[src] + sd;
                t = t > 0.f ? t : NEG_SLOPE * t;
                w = expf(t - m);
            }
        }
        den += w;
        int steps = (cnt + 3) >> 2;
        for (int j = 0; j < steps; ++j) {
            int e = j * 4 + g;
            int idx = min(e, cnt - 1);
            float wj = __shfl(w, idx);
            int  sj  = __shfl(src, idx);
            if (e >= cnt) wj = 0.f;
            uint4 hv = ((const uint4*)(hu + (size_t)sj * 128))[c];
            acc[0] += wj * bflo(hv.x); acc[1] += wj * bfhi(hv.x);
            acc[2] += wj * bflo(hv.y); acc[3] += wj * bfhi(hv.y);
            acc[4] += wj * bflo(hv.z); acc[5] += wj * bfhi(hv.z);
            acc[6] += wj * bflo(hv.w); acc[7] += wj * bfhi(hv.w);
        }
    }
    #pragma unroll
    for (int o = 32; o; o >>= 1) den += __shfl_xor(den, o);
    #pragma unroll
    for (int k = 0; k < 8; ++k) {
        acc[k] += __shfl_xor(acc[k], 16);
        acc[k] += __shfl_xor(acc[k], 32);
    }
    if (g == 0) {
        float o8[8];
        #pragma unroll
        for (int k = 0; k < 8; ++k) {
            float v = acc[k] / den + bias[c * 8 + k];
            o8[k] = v > 0.f ? v : (expf(v) - 1.f);
        }
        float* op = out + (size_t)wid * 128 + c * 8;
        *(float4*)op       = make_float4(o8[0], o8[1], o8[2], o8[3]);
        *(float4*)(op + 4) = make_float4(o8[4], o8[5], o8[6], o8[7]);
    }
}

// ---------------- pooling: one block per graph (batch is sorted) ------------
__global__ void pool_graph(const float* __restrict__ y, const int* __restrict__ batch,
                           float* __restrict__ out, int n, int G) {
    int g = blockIdx.x;
    int lo = 0, hi = n;
    while (lo < hi) { int mid = (lo + hi) >> 1; if (batch[mid] < g) lo = mid + 1; else hi = mid; }
    int beg = lo;
    hi = n;
    while (lo < hi) { int mid = (lo + hi) >> 1; if (batch[mid] < g + 1) lo = mid + 1; else hi = mid; }
    int end = lo;

    int c = threadIdx.x & 31;
    int sub = threadIdx.x >> 5;
    float acc = 0.f;
    for (int node = beg + sub; node < end; node += 8)
        acc += y[(size_t)node * 32 + c];

    __shared__ float ls[8][32];
    ls[sub][c] = acc;
    __syncthreads();
    if (sub == 0) {
        float s = 0.f;
        #pragma unroll
        for (int k = 0; k < 8; ++k) s += ls[k][c];
        out[g * 32 + c] = s / fmaxf((float)(end - beg), 1.f);
    }
}

extern "C" void kernel_launch(void* const* d_in, const int* in_sizes, int n_in,
                              void* d_out, int out_size, void* d_ws, size_t ws_size,
                              hipStream_t stream) {
    const float* pos  = (const float*)d_in[0];
    const int*   z    = (const int*)d_in[1];
    const int*   ei   = (const int*)d_in[2];
    const int*   batch= (const int*)d_in[3];
    const float* emb  = (const float*)d_in[4];
    const float* W1   = (const float*)d_in[5];
    const float* a1s  = (const float*)d_in[6];
    const float* a1d  = (const float*)d_in[7];
    const float* b1   = (const float*)d_in[8];
    const float* W2   = (const float*)d_in[9];
    const float* a2s  = (const float*)d_in[10];
    const float* a2d  = (const float*)d_in[11];
    const float* b2   = (const float*)d_in[12];
    const float* Wlin = (const float*)d_in[13];
    const float* blin = (const float*)d_in[14];

    const int N = in_sizes[0] / 3;        // 50000
    const int E = in_sizes[2] / 2;        // 1600000
    const int Etot = E + N;
    const int G = out_size / 32;          // 64
    const int nbins = ((N - 1) >> BIN_SHIFT) + 1;   // 196

    char* ws = (char*)d_ws;
    size_t NB = (size_t)N * 128 * sizeof(float);
    float* buf0   = (float*)ws;                    // x / h2 / y  (pairs aliases this pre-build_x)
    float* buf1   = (float*)(ws + NB);             // h1 / out2
    float* buf2   = (float*)(ws + 2 * NB);         // out1 (=x for layer2)
    float* ssrc   = (float*)(ws + 3 * NB);
    float* sdst   = ssrc + N;
    int*   rowptr = (int*)(sdst + N);              // N+1
    int*   binCnt = rowptr + N + 1;                // 256
    int*   binBase= binCnt + 256;                  // 257
    int*   binCur = binBase + 257;                 // 256
    int*   csrs   = binCur + 256;                  // Etot
    uintptr_t hp  = (uintptr_t)(csrs + Etot);
    hp = (hp + 255) & ~(uintptr_t)255;             // 256B-align for uint4 rows
    __hip_bfloat16* hbf = (__hip_bfloat16*)hp;     // N*128 bf16
    uint2* pairs  = (uint2*)buf0;                  // Etot uint2 (13.2MB < 25.6MB)

    const int TB = 256;
    dim3 blk(TB);
    int gElem  = (N * 128 + TB - 1) / TB;
    int gNodeW = ((size_t)N * 64 + TB - 1) / TB;
    int gGemmT = (N + 127) / 128;
    int gGemmO = (N + 63) / 64;
    int gGat   = (N + 3) / 4;
    int nchunk = (Etot + CHUNK - 1) / CHUNK;       // 202

    // ---------- CSR build: two-level dst binning ----------
    hipMemsetAsync(binCnt, 0, 256 * sizeof(int), stream);
    bin_hist<<<nchunk, blk, 0, stream>>>(ei, E, N, nbins, binCnt);
    bin_scan<<<1, blk, 0, stream>>>(binCnt, nbins, binBase, binCur, rowptr, N, Etot);
    bin_scatter<<<nchunk, blk, 0, stream>>>(ei, E, N, nbins, binCur, pairs);
    bin_finalize<<<nbins, blk, 0, stream>>>(pairs, binBase, rowptr, csrs, N);

    // ---------- layer 1 ----------
    build_x<<<gElem, blk, 0, stream>>>(pos, z, emb, buf0, N);
    gemm128_tiled<<<gGemmT, blk, 0, stream>>>(buf0, W1, buf1, hbf, N);
    node_dots<<<gNodeW, blk, 0, stream>>>(buf1, a1s, a1d, ssrc, sdst, N);
    gat_gather<<<gGat, blk, 0, stream>>>(rowptr, csrs, ssrc, sdst, hbf, b1, buf2, N);

    // ---------- layer 2 ----------
    gemm128_tiled<<<gGemmT, blk, 0, stream>>>(buf2, W2, buf0, hbf, N);
    node_dots<<<gNodeW, blk, 0, stream>>>(buf0, a2s, a2d, ssrc, sdst, N);
    gat_gather<<<gGat, blk, 0, stream>>>(rowptr, csrs, ssrc, sdst, hbf, b2, buf1, N);

    // ---------- linear + pool ----------
    gemm_x128<32, 64><<<gGemmO, blk, 0, stream>>>(buf1, Wlin, blin, buf0, N);
    pool_graph<<<G, blk, 0, stream>>>(buf0, batch, (float*)d_out, N, G);
}